// Round 10
// baseline (185.622 us; speedup 1.0000x reference)
//
#include <hip/hip_runtime.h>
#include <math.h>

#define NN 50000
#define NE 1000000
#define NH 64
#define NKEY 100000      // 2*NN combined key space (src | NN+dst)
#define SPAN 512         // keys per bucket
#define NBKT 196         // ceil(NKEY / SPAN)
#define CAP 12288        // bucket capacity (mean 10240, +20 sigma)
#define CH 34            // LDS staging entries per bucket
#define GNPB 64          // nodes per block in node_gemm

// ---------- binning helpers -------------------------------------------------
__device__ __forceinline__ void push_pair(int key, int val, int* cnt,
                                          unsigned* buf, int* gcnt,
                                          unsigned* __restrict__ pairs) {
    int b = key >> 9;
    unsigned pk = ((unsigned)val << 9) | (unsigned)(key & 511);
    int slot = atomicAdd(&cnt[b], 1);           // LDS atomic
    if (slot < CH) {
        buf[b * CH + slot] = pk;
    } else {                                     // rare overflow: direct path
        int g = atomicAdd(&gcnt[b], 1);
        if (g < CAP) pairs[(size_t)b * CAP + g] = pk;
    }
}

__device__ __forceinline__ void flush_bins(int* cnt, unsigned* buf, int* gcnt,
                                           unsigned* __restrict__ pairs) {
    __syncthreads();
    int b = threadIdx.x;
    if (b < NBKT) {
        int fc = cnt[b]; if (fc > CH) fc = CH;
        if (fc > 0) {
            int g = atomicAdd(&gcnt[b], fc);     // one global atomic per run
            for (int t = 0; t < fc; ++t)
                if (g + t < CAP)
                    pairs[(size_t)b * CAP + g + t] = buf[b * CH + t];
            cnt[b] = 0;
        }
    }
    __syncthreads();
}

// ---------- pass 1: LDS-staged binning of 2M (key,val) pairs ----------------
__global__ __launch_bounds__(256) void bin_pass(
    const int* __restrict__ src, const int* __restrict__ dst,
    int* __restrict__ gcnt, unsigned* __restrict__ pairs) {
    __shared__ int cnt[NBKT];
    __shared__ unsigned buf[NBKT * CH];
    for (int b = threadIdx.x; b < NBKT; b += 256) cnt[b] = 0;
    __syncthreads();
    int r = 0;
    for (int base = blockIdx.x * 256; base < NE; base += gridDim.x * 256) {
        int e = base + threadIdx.x;
        if (e < NE) {
            int s = src[e], d = dst[e];
            push_pair(s, d, cnt, buf, gcnt, pairs);       // out-edge of s
            push_pair(NN + d, s, cnt, buf, gcnt, pairs);  // in-edge of d
        }
        if ((++r & 7) == 0) flush_bins(cnt, buf, gcnt, pairs);
    }
    flush_bins(cnt, buf, gcnt, pairs);
}

// ---------- pass 2: scan 196 bucket counts ----------------------------------
__global__ __launch_bounds__(256) void bucket_scan(
    const int* __restrict__ gcnt, int* __restrict__ gbase,
    int* __restrict__ off) {
    __shared__ int tmp[256];
    int t = threadIdx.x;
    int v = (t < NBKT) ? gcnt[t] : 0;
    tmp[t] = v;
    __syncthreads();
    for (int o = 1; o < 256; o <<= 1) {
        int u = (t >= o) ? tmp[t - o] : 0;
        __syncthreads();
        tmp[t] += u;
        __syncthreads();
    }
    if (t < NBKT) gbase[t] = tmp[t] - v;   // exclusive prefix
    if (t == 0) off[NKEY] = 2 * NE;        // sentinel
}

// ---------- pass 3: per-bucket counting sort + off/csr emission -------------
__global__ __launch_bounds__(1024) void sort_pass(
    const unsigned* __restrict__ pairs, const int* __restrict__ gcnt,
    const int* __restrict__ gbase, int* __restrict__ off,
    int* __restrict__ csr) {
    __shared__ int hist[SPAN];
    __shared__ int scn[SPAN];
    int k = blockIdx.x;
    int t = threadIdx.x;
    int n = gcnt[k]; if (n > CAP) n = CAP;
    int base = gbase[k];
    const unsigned* bp = pairs + (size_t)k * CAP;

    if (t < SPAN) hist[t] = 0;
    __syncthreads();
    for (int i = t; i < n; i += 1024)
        atomicAdd(&hist[bp[i] & 511], 1);
    __syncthreads();
    if (t < SPAN) scn[t] = hist[t];
    __syncthreads();
    for (int o = 1; o < SPAN; o <<= 1) {
        int u = 0;
        if (t < SPAN && t >= o) u = scn[t - o];
        __syncthreads();
        if (t < SPAN) scn[t] += u;
        __syncthreads();
    }
    if (t < SPAN) {
        int ex = base + scn[t] - hist[t];   // absolute exclusive prefix
        int gk = k * SPAN + t;
        if (gk < NKEY) off[gk] = ex;
        scn[t] = ex;                        // reuse as cursor
    }
    __syncthreads();
    for (int i = t; i < n; i += 1024) {
        unsigned p = bp[i];
        int pos = atomicAdd(&scn[p & 511], 1);   // LDS atomic
        csr[pos] = (int)(p >> 9);                // block-local global store
    }
}

// clamp gathered index (protects rocprof dispatch-replay from stale buffers;
// compiles to v_med3_i32, free in a latency-bound gather loop)
__device__ __forceinline__ int cidx(int i) {
    return max(0, min(i, NN - 1));
}

// ---------- pass 4: wave-per-node gather-mean, 8-deep ILP -------------------
__global__ __launch_bounds__(256) void gather_mean(
    const float* __restrict__ X, const int* __restrict__ off_dst,
    const int* __restrict__ csr, float* __restrict__ M) {
    int wid = (int)(((long long)blockIdx.x * blockDim.x + threadIdx.x) >> 6);
    int j = threadIdx.x & 63;
    if (wid >= NN) return;
    int e0 = off_dst[wid], e1 = off_dst[wid + 1];
    const float* Xj = X + j;
    float s0 = 0, s1 = 0, s2 = 0, s3 = 0, s4 = 0, s5 = 0, s6 = 0, s7 = 0;
    int e = e0;
    for (; e + 8 <= e1; e += 8) {
        int i0 = cidx(csr[e + 0]), i1 = cidx(csr[e + 1]);
        int i2 = cidx(csr[e + 2]), i3 = cidx(csr[e + 3]);
        int i4 = cidx(csr[e + 4]), i5 = cidx(csr[e + 5]);
        int i6 = cidx(csr[e + 6]), i7 = cidx(csr[e + 7]);
        s0 += Xj[(size_t)i0 * NH]; s1 += Xj[(size_t)i1 * NH];
        s2 += Xj[(size_t)i2 * NH]; s3 += Xj[(size_t)i3 * NH];
        s4 += Xj[(size_t)i4 * NH]; s5 += Xj[(size_t)i5 * NH];
        s6 += Xj[(size_t)i6 * NH]; s7 += Xj[(size_t)i7 * NH];
    }
    for (; e < e1; ++e) s0 += Xj[(size_t)cidx(csr[e]) * NH];
    float sum = ((s0 + s1) + (s2 + s3)) + ((s4 + s5) + (s6 + s7));
    M[(size_t)wid * NH + j] = sum / fmaxf((float)(e1 - e0), 1.0f);
}

// ---------- pass 5: node GEMM v6 — scalar-loaded weights, minimal LDS -------
// 256 threads = 4 waves per 64-node block. Wave w owns output cols
// 16w..16w+15 (wave-uniform -> weights via s_load, zero LDS/VMEM-per-lane);
// lane = node. LDS holds only x/mean/h (35 KB, XOR-swizzled float4 slots).
__global__ __launch_bounds__(256, 4) void node_gemm(
    const float* __restrict__ X, float* MA /* in: mean, out: A (aliased) */,
    const float* __restrict__ Wself, const float* __restrict__ Wneigh,
    const float* __restrict__ bsage, const float* __restrict__ Qw,
    float* __restrict__ B) {
    __shared__ float4 sx4[64 * 17];   // x    [node][slot^swz]
    __shared__ float4 sm4[64 * 17];   // mean, then h

    const int T    = threadIdx.x;
    const int lane = T & 63;                                   // node in block
    const int cg   = __builtin_amdgcn_readfirstlane(T >> 6);   // wave: col grp
    const int nbase = blockIdx.x * GNPB;

    // stage x, mean (coalesced float4 reads, swizzled LDS placement)
    #pragma unroll
    for (int r = 0; r < 4; ++r) {
        int F = r * 256 + T;            // 0..1023
        int node = F >> 4, k4 = F & 15;
        int gn = nbase + node; if (gn > NN - 1) gn = NN - 1;
        int u = node * 17 + (k4 ^ (node & 7));
        sx4[u] = ((const float4*)&X[(size_t)gn * NH])[k4];
        sm4[u] = ((const float4*)&MA[(size_t)gn * NH])[k4];
    }
    __syncthreads();

    const float* WsC = Wself + cg * 16;      // uniform pointers -> s_load
    const float* WnC = Wneigh + cg * 16;
    const float* Q1C = Qw + cg * 16;         // Q_w rows 0..63
    const float* Q2C = Qw + 4096 + cg * 16;  // Q_w rows 64..127

    const int rbase = lane * 17;
    const int rx = lane & 7;

    // ---- phase 1: h = relu(x Ws + m Wn + b) ----
    float acc[16];
    #pragma unroll
    for (int i = 0; i < 4; ++i) {
        float4 b4 = ((const float4*)bsage)[cg * 4 + i];
        acc[i*4+0] = b4.x; acc[i*4+1] = b4.y;
        acc[i*4+2] = b4.z; acc[i*4+3] = b4.w;
    }
    #pragma unroll 2
    for (int q = 0; q < 16; ++q) {
        float4 xv = sx4[rbase + (q ^ rx)];
        float4 mv = sm4[rbase + (q ^ rx)];
        #pragma unroll
        for (int kk = 0; kk < 4; ++kk) {
            int k = q * 4 + kk;
            float xs = ((const float*)&xv)[kk];
            float ms = ((const float*)&mv)[kk];
            #pragma unroll
            for (int jj = 0; jj < 16; ++jj)
                acc[jj] += xs * WsC[k * 64 + jj] + ms * WnC[k * 64 + jj];
        }
    }
    __syncthreads();    // all mean reads done

    // write h over the mean slot (same swizzle; waves cover slots 4cg..4cg+3)
    #pragma unroll
    for (int i = 0; i < 4; ++i) {
        float4 hv;
        hv.x = fmaxf(acc[i*4+0], 0.0f);
        hv.y = fmaxf(acc[i*4+1], 0.0f);
        hv.z = fmaxf(acc[i*4+2], 0.0f);
        hv.w = fmaxf(acc[i*4+3], 0.0f);
        sm4[rbase + ((cg * 4 + i) ^ rx)] = hv;
    }
    __syncthreads();

    // ---- phase 2: A = h Q1, B = h Q2 ----
    float aA[16], aB[16];
    #pragma unroll
    for (int jj = 0; jj < 16; ++jj) { aA[jj] = 0.0f; aB[jj] = 0.0f; }

    #pragma unroll 2
    for (int q = 0; q < 16; ++q) {
        float4 hv = sm4[rbase + (q ^ rx)];
        #pragma unroll
        for (int kk = 0; kk < 4; ++kk) {
            int k = q * 4 + kk;
            float hs = ((const float*)&hv)[kk];
            #pragma unroll
            for (int jj = 0; jj < 16; ++jj) {
                aA[jj] += hs * Q1C[k * 64 + jj];
                aB[jj] += hs * Q2C[k * 64 + jj];
            }
        }
    }

    // store A (over mean) and B; each wave writes one 64B line per row
    int gn = nbase + lane;
    if (gn < NN) {
        #pragma unroll
        for (int i = 0; i < 4; ++i) {
            float4 va, vb;
            va.x = aA[i*4+0]; va.y = aA[i*4+1]; va.z = aA[i*4+2]; va.w = aA[i*4+3];
            vb.x = aB[i*4+0]; vb.y = aB[i*4+1]; vb.z = aB[i*4+2]; vb.w = aB[i*4+3];
            ((float4*)&MA[(size_t)gn * NH])[cg * 4 + i] = va;
            ((float4*)&B[(size_t)gn * NH])[cg * 4 + i] = vb;
        }
    }
}

// ---------- pass 6: wave-per-node out-edge reduction, 8-deep ILP ------------
__global__ __launch_bounds__(256) void edge_out(
    const float* __restrict__ A, const float* __restrict__ B,
    const float* __restrict__ Qb, const int* __restrict__ off_src,
    const int* __restrict__ csr, float* __restrict__ out) {
    int wid = (int)(((long long)blockIdx.x * blockDim.x + threadIdx.x) >> 6);
    int j = threadIdx.x & 63;
    if (wid >= NN) return;
    float aq = A[(size_t)wid * NH + j] + Qb[j];
    int e0 = off_src[wid], e1 = off_src[wid + 1];
    const float* Bj = B + j;
    float s0 = 0, s1 = 0, s2 = 0, s3 = 0, s4 = 0, s5 = 0, s6 = 0, s7 = 0;
    int e = e0;
    for (; e + 8 <= e1; e += 8) {
        int i0 = cidx(csr[e + 0]), i1 = cidx(csr[e + 1]);
        int i2 = cidx(csr[e + 2]), i3 = cidx(csr[e + 3]);
        int i4 = cidx(csr[e + 4]), i5 = cidx(csr[e + 5]);
        int i6 = cidx(csr[e + 6]), i7 = cidx(csr[e + 7]);
        float t0 = aq + Bj[(size_t)i0 * NH]; s0 += t0 * t0;
        float t1 = aq + Bj[(size_t)i1 * NH]; s1 += t1 * t1;
        float t2 = aq + Bj[(size_t)i2 * NH]; s2 += t2 * t2;
        float t3 = aq + Bj[(size_t)i3 * NH]; s3 += t3 * t3;
        float t4 = aq + Bj[(size_t)i4 * NH]; s4 += t4 * t4;
        float t5 = aq + Bj[(size_t)i5 * NH]; s5 += t5 * t5;
        float t6 = aq + Bj[(size_t)i6 * NH]; s6 += t6 * t6;
        float t7 = aq + Bj[(size_t)i7 * NH]; s7 += t7 * t7;
    }
    for (; e < e1; ++e) {
        float t = aq + Bj[(size_t)cidx(csr[e]) * NH];
        s0 += t * t;
    }
    float acc = ((s0 + s1) + (s2 + s3)) + ((s4 + s5) + (s6 + s7));
    out[(size_t)wid * NH + j] = tanhf(acc / fmaxf((float)(e1 - e0), 1.0f));
}

extern "C" void kernel_launch(void* const* d_in, const int* in_sizes, int n_in,
                              void* d_out, int out_size, void* d_ws, size_t ws_size,
                              hipStream_t stream) {
    const float* X      = (const float*)d_in[0];
    const int*   ei     = (const int*)d_in[1];   // [2, NE] int32
    const float* Wself  = (const float*)d_in[2];
    const float* Wneigh = (const float*)d_in[3];
    const float* bsage  = (const float*)d_in[4];
    const float* Qw     = (const float*)d_in[5];
    const float* Qb     = (const float*)d_in[6];
    const int* src = ei;
    const int* dst = ei + NE;

    float* out = (float*)d_out;

    // workspace layout (~44 MB)
    float* A = (float*)d_ws;                         // NN*NH floats
    float* B = A + (size_t)NN * NH;                  // NN*NH floats
    unsigned* pairs = (unsigned*)(B + (size_t)NN * NH); // NBKT*CAP u32
    int* csr   = (int*)(pairs + (size_t)NBKT * CAP); // 2*NE
    int* off   = csr + 2 * NE;                       // NKEY+1
    int* gcnt  = off + NKEY + 1;                     // NBKT
    int* gbase = gcnt + NBKT;                        // NBKT

    hipMemsetAsync(gcnt, 0, NBKT * sizeof(int), stream);

    bin_pass<<<512, 256, 0, stream>>>(src, dst, gcnt, pairs);
    bucket_scan<<<1, 256, 0, stream>>>(gcnt, gbase, off);
    sort_pass<<<NBKT, 1024, 0, stream>>>(pairs, gcnt, gbase, off, csr);
    gather_mean<<<(NN + 3) / 4, 256, 0, stream>>>(X, off + NN, csr, A);
    node_gemm<<<(NN + GNPB - 1) / GNPB, 256, 0, stream>>>(X, A, Wself, Wneigh,
                                                          bsage, Qw, B);
    edge_out<<<(NN + 3) / 4, 256, 0, stream>>>(A, B, Qb, off, csr, out);
}

// Round 11
// 179.793 us; speedup vs baseline: 1.0324x; 1.0324x over previous
//
#include <hip/hip_runtime.h>
#include <math.h>

#define NN 50000
#define NE 1000000
#define NH 64
#define NKEY 100000      // 2*NN combined key space (src | NN+dst)
#define SPAN 512         // keys per bucket
#define NBKT 196         // ceil(NKEY / SPAN)
#define CAP 12288        // bucket capacity (mean 10240, +20 sigma)
#define CH 34            // LDS staging entries per bucket
#define GNPB 64          // nodes per block in node_gemm

// ---------- binning helpers -------------------------------------------------
__device__ __forceinline__ void push_pair(int key, int val, int* cnt,
                                          unsigned* buf, int* gcnt,
                                          unsigned* __restrict__ pairs) {
    int b = key >> 9;
    unsigned pk = ((unsigned)val << 9) | (unsigned)(key & 511);
    int slot = atomicAdd(&cnt[b], 1);           // LDS atomic
    if (slot < CH) {
        buf[b * CH + slot] = pk;
    } else {                                     // rare overflow: direct path
        int g = atomicAdd(&gcnt[b], 1);
        if (g < CAP) pairs[(size_t)b * CAP + g] = pk;
    }
}

__device__ __forceinline__ void flush_bins(int* cnt, unsigned* buf, int* gcnt,
                                           unsigned* __restrict__ pairs) {
    __syncthreads();
    int b = threadIdx.x;
    if (b < NBKT) {
        int fc = cnt[b]; if (fc > CH) fc = CH;
        if (fc > 0) {
            int g = atomicAdd(&gcnt[b], fc);     // one global atomic per run
            for (int t = 0; t < fc; ++t)
                if (g + t < CAP)
                    pairs[(size_t)b * CAP + g + t] = buf[b * CH + t];
            cnt[b] = 0;
        }
    }
    __syncthreads();
}

// ---------- pass 1: LDS-staged binning of 2M (key,val) pairs ----------------
__global__ __launch_bounds__(256) void bin_pass(
    const int* __restrict__ src, const int* __restrict__ dst,
    int* __restrict__ gcnt, unsigned* __restrict__ pairs) {
    __shared__ int cnt[NBKT];
    __shared__ unsigned buf[NBKT * CH];
    for (int b = threadIdx.x; b < NBKT; b += 256) cnt[b] = 0;
    __syncthreads();
    int r = 0;
    for (int base = blockIdx.x * 256; base < NE; base += gridDim.x * 256) {
        int e = base + threadIdx.x;
        if (e < NE) {
            int s = src[e], d = dst[e];
            push_pair(s, d, cnt, buf, gcnt, pairs);       // out-edge of s
            push_pair(NN + d, s, cnt, buf, gcnt, pairs);  // in-edge of d
        }
        if ((++r & 7) == 0) flush_bins(cnt, buf, gcnt, pairs);
    }
    flush_bins(cnt, buf, gcnt, pairs);
}

// ---------- pass 2: scan 196 bucket counts ----------------------------------
__global__ __launch_bounds__(256) void bucket_scan(
    const int* __restrict__ gcnt, int* __restrict__ gbase,
    int* __restrict__ off) {
    __shared__ int tmp[256];
    int t = threadIdx.x;
    int v = (t < NBKT) ? gcnt[t] : 0;
    tmp[t] = v;
    __syncthreads();
    for (int o = 1; o < 256; o <<= 1) {
        int u = (t >= o) ? tmp[t - o] : 0;
        __syncthreads();
        tmp[t] += u;
        __syncthreads();
    }
    if (t < NBKT) gbase[t] = tmp[t] - v;   // exclusive prefix
    if (t == 0) off[NKEY] = 2 * NE;        // sentinel
}

// ---------- pass 3: per-bucket counting sort + off/csr emission -------------
__global__ __launch_bounds__(1024) void sort_pass(
    const unsigned* __restrict__ pairs, const int* __restrict__ gcnt,
    const int* __restrict__ gbase, int* __restrict__ off,
    int* __restrict__ csr) {
    __shared__ int hist[SPAN];
    __shared__ int scn[SPAN];
    int k = blockIdx.x;
    int t = threadIdx.x;
    int n = gcnt[k]; if (n > CAP) n = CAP;
    int base = gbase[k];
    const unsigned* bp = pairs + (size_t)k * CAP;

    if (t < SPAN) hist[t] = 0;
    __syncthreads();
    for (int i = t; i < n; i += 1024)
        atomicAdd(&hist[bp[i] & 511], 1);
    __syncthreads();
    if (t < SPAN) scn[t] = hist[t];
    __syncthreads();
    for (int o = 1; o < SPAN; o <<= 1) {
        int u = 0;
        if (t < SPAN && t >= o) u = scn[t - o];
        __syncthreads();
        if (t < SPAN) scn[t] += u;
        __syncthreads();
    }
    if (t < SPAN) {
        int ex = base + scn[t] - hist[t];   // absolute exclusive prefix
        int gk = k * SPAN + t;
        if (gk < NKEY) off[gk] = ex;
        scn[t] = ex;                        // reuse as cursor
    }
    __syncthreads();
    for (int i = t; i < n; i += 1024) {
        unsigned p = bp[i];
        int pos = atomicAdd(&scn[p & 511], 1);   // LDS atomic
        csr[pos] = (int)(p >> 9);                // block-local global store
    }
}

// clamp gathered index (protects rocprof dispatch-replay from stale buffers;
// compiles to v_med3_i32, free in a latency-bound gather loop)
__device__ __forceinline__ int cidx(int i) {
    return max(0, min(i, NN - 1));
}

// ---------- pass 4: wave-per-node gather-mean, 8-deep ILP -------------------
__global__ __launch_bounds__(256) void gather_mean(
    const float* __restrict__ X, const int* __restrict__ off_dst,
    const int* __restrict__ csr, float* __restrict__ M) {
    int wid = (int)(((long long)blockIdx.x * blockDim.x + threadIdx.x) >> 6);
    int j = threadIdx.x & 63;
    if (wid >= NN) return;
    int e0 = off_dst[wid], e1 = off_dst[wid + 1];
    const float* Xj = X + j;
    float s0 = 0, s1 = 0, s2 = 0, s3 = 0, s4 = 0, s5 = 0, s6 = 0, s7 = 0;
    int e = e0;
    for (; e + 8 <= e1; e += 8) {
        int i0 = cidx(csr[e + 0]), i1 = cidx(csr[e + 1]);
        int i2 = cidx(csr[e + 2]), i3 = cidx(csr[e + 3]);
        int i4 = cidx(csr[e + 4]), i5 = cidx(csr[e + 5]);
        int i6 = cidx(csr[e + 6]), i7 = cidx(csr[e + 7]);
        s0 += Xj[(size_t)i0 * NH]; s1 += Xj[(size_t)i1 * NH];
        s2 += Xj[(size_t)i2 * NH]; s3 += Xj[(size_t)i3 * NH];
        s4 += Xj[(size_t)i4 * NH]; s5 += Xj[(size_t)i5 * NH];
        s6 += Xj[(size_t)i6 * NH]; s7 += Xj[(size_t)i7 * NH];
    }
    for (; e < e1; ++e) s0 += Xj[(size_t)cidx(csr[e]) * NH];
    float sum = ((s0 + s1) + (s2 + s3)) + ((s4 + s5) + (s6 + s7));
    M[(size_t)wid * NH + j] = sum / fmaxf((float)(e1 - e0), 1.0f);
}

// ---------- pass 5: node GEMM v7 — 8x4 tile, XOR-swizzled LDS, 2 blocks/CU --
// 128 threads (2 waves), 64 nodes/block. LDS: 2-stage weights (32 KB) +
// x/h tiles (35 KB, float4 slots XOR-swizzled by (row>>3)&7 so the 4
// 8-row-apart addresses per read instr land in distinct bank groups).
__global__ __launch_bounds__(128) void node_gemm(
    const float* __restrict__ X, float* MA /* in: mean, out: A (aliased) */,
    const float* __restrict__ Wself, const float* __restrict__ Wneigh,
    const float* __restrict__ bsage, const float* __restrict__ Qw,
    float* __restrict__ B) {
    __shared__ __align__(16) float sWa[4096];   // Ws, then Q1  [k][j]
    __shared__ __align__(16) float sWb[4096];   // Wn, then Q2  [k][j]
    __shared__ float4 sx4[64 * 17];             // x    [row][slot^swz]
    __shared__ float4 sh4[64 * 17];             // mean, then h

    const int T  = threadIdx.x;
    const int tj = T & 15;          // cols 4*tj..4*tj+3
    const int tn = T >> 4;          // nodes 8*tn..8*tn+7 (tn 0..7)
    const int nbase = blockIdx.x * GNPB;

    // stage Ws, Wn (1024 float4 each)
    #pragma unroll
    for (int r = 0; r < 8; ++r) {
        int i = r * 128 + T;
        ((float4*)sWa)[i] = ((const float4*)Wself)[i];
        ((float4*)sWb)[i] = ((const float4*)Wneigh)[i];
    }
    // stage x, mean (coalesced float4; swizzled slot placement)
    #pragma unroll
    for (int r = 0; r < 8; ++r) {
        int F = r * 128 + T;        // 0..1023
        int node = F >> 4, k4 = F & 15;
        int gn = nbase + node; if (gn > NN - 1) gn = NN - 1;
        int u = node * 17 + (k4 ^ ((node >> 3) & 7));
        sx4[u] = ((const float4*)&X[(size_t)gn * NH])[k4];
        sh4[u] = ((const float4*)&MA[(size_t)gn * NH])[k4];
    }
    __syncthreads();

    const int swz = tn & 7;         // == (row>>3)&7 for rows tn*8+ni

    // ---- phase 1: h = relu(x Ws + m Wn + b) ----
    float4 bv = ((const float4*)bsage)[tj];
    float acc[8][4];
    #pragma unroll
    for (int ni = 0; ni < 8; ++ni) {
        acc[ni][0] = bv.x; acc[ni][1] = bv.y;
        acc[ni][2] = bv.z; acc[ni][3] = bv.w;
    }

    for (int q = 0; q < 16; ++q) {
        float4 xr[8], mr[8], wa[4], wb[4];
        #pragma unroll
        for (int ni = 0; ni < 8; ++ni) {
            int u = (tn * 8 + ni) * 17 + (q ^ swz);
            xr[ni] = sx4[u];
            mr[ni] = sh4[u];
        }
        #pragma unroll
        for (int kk = 0; kk < 4; ++kk) {
            wa[kk] = ((const float4*)sWa)[(q * 4 + kk) * 16 + tj];
            wb[kk] = ((const float4*)sWb)[(q * 4 + kk) * 16 + tj];
        }
        #pragma unroll
        for (int ni = 0; ni < 8; ++ni)
            #pragma unroll
            for (int kk = 0; kk < 4; ++kk) {
                float xs = ((const float*)&xr[ni])[kk];
                float ms = ((const float*)&mr[ni])[kk];
                #pragma unroll
                for (int ji = 0; ji < 4; ++ji)
                    acc[ni][ji] += xs * ((const float*)&wa[kk])[ji]
                                 + ms * ((const float*)&wb[kk])[ji];
            }
    }
    __syncthreads();   // all mean + Ws/Wn reads done

    // write h = relu(acc) into sh4 (same swizzle); re-stage Q1/Q2
    #pragma unroll
    for (int ni = 0; ni < 8; ++ni) {
        float4 hv;
        hv.x = fmaxf(acc[ni][0], 0.0f);
        hv.y = fmaxf(acc[ni][1], 0.0f);
        hv.z = fmaxf(acc[ni][2], 0.0f);
        hv.w = fmaxf(acc[ni][3], 0.0f);
        sh4[(tn * 8 + ni) * 17 + (tj ^ swz)] = hv;
    }
    #pragma unroll
    for (int r = 0; r < 8; ++r) {
        int i = r * 128 + T;
        ((float4*)sWa)[i] = ((const float4*)Qw)[i];           // rows 0..63
        ((float4*)sWb)[i] = ((const float4*)(Qw + 4096))[i];  // rows 64..127
    }
    __syncthreads();

    // ---- phase 2: A = h Q1, B = h Q2 ----
    float aA[8][4], aB[8][4];
    #pragma unroll
    for (int ni = 0; ni < 8; ++ni)
        #pragma unroll
        for (int ji = 0; ji < 4; ++ji) { aA[ni][ji] = 0.0f; aB[ni][ji] = 0.0f; }

    for (int q = 0; q < 16; ++q) {
        float4 hr[8], q1[4], q2[4];
        #pragma unroll
        for (int ni = 0; ni < 8; ++ni)
            hr[ni] = sh4[(tn * 8 + ni) * 17 + (q ^ swz)];
        #pragma unroll
        for (int jj = 0; jj < 4; ++jj) {
            q1[jj] = ((const float4*)sWa)[(q * 4 + jj) * 16 + tj];
            q2[jj] = ((const float4*)sWb)[(q * 4 + jj) * 16 + tj];
        }
        #pragma unroll
        for (int ni = 0; ni < 8; ++ni)
            #pragma unroll
            for (int jj = 0; jj < 4; ++jj) {
                float hs = ((const float*)&hr[ni])[jj];
                #pragma unroll
                for (int ji = 0; ji < 4; ++ji) {
                    aA[ni][ji] += hs * ((const float*)&q1[jj])[ji];
                    aB[ni][ji] += hs * ((const float*)&q2[jj])[ji];
                }
            }
    }

    // store A (over mean) and B
    #pragma unroll
    for (int ni = 0; ni < 8; ++ni) {
        int gn = nbase + tn * 8 + ni;
        if (gn < NN) {
            float4 va, vb;
            va.x = aA[ni][0]; va.y = aA[ni][1]; va.z = aA[ni][2]; va.w = aA[ni][3];
            vb.x = aB[ni][0]; vb.y = aB[ni][1]; vb.z = aB[ni][2]; vb.w = aB[ni][3];
            *(float4*)&MA[(size_t)gn * NH + tj * 4] = va;
            *(float4*)&B[(size_t)gn * NH + tj * 4] = vb;
        }
    }
}

// ---------- pass 6: wave-per-node out-edge reduction, 8-deep ILP ------------
__global__ __launch_bounds__(256) void edge_out(
    const float* __restrict__ A, const float* __restrict__ B,
    const float* __restrict__ Qb, const int* __restrict__ off_src,
    const int* __restrict__ csr, float* __restrict__ out) {
    int wid = (int)(((long long)blockIdx.x * blockDim.x + threadIdx.x) >> 6);
    int j = threadIdx.x & 63;
    if (wid >= NN) return;
    float aq = A[(size_t)wid * NH + j] + Qb[j];
    int e0 = off_src[wid], e1 = off_src[wid + 1];
    const float* Bj = B + j;
    float s0 = 0, s1 = 0, s2 = 0, s3 = 0, s4 = 0, s5 = 0, s6 = 0, s7 = 0;
    int e = e0;
    for (; e + 8 <= e1; e += 8) {
        int i0 = cidx(csr[e + 0]), i1 = cidx(csr[e + 1]);
        int i2 = cidx(csr[e + 2]), i3 = cidx(csr[e + 3]);
        int i4 = cidx(csr[e + 4]), i5 = cidx(csr[e + 5]);
        int i6 = cidx(csr[e + 6]), i7 = cidx(csr[e + 7]);
        float t0 = aq + Bj[(size_t)i0 * NH]; s0 += t0 * t0;
        float t1 = aq + Bj[(size_t)i1 * NH]; s1 += t1 * t1;
        float t2 = aq + Bj[(size_t)i2 * NH]; s2 += t2 * t2;
        float t3 = aq + Bj[(size_t)i3 * NH]; s3 += t3 * t3;
        float t4 = aq + Bj[(size_t)i4 * NH]; s4 += t4 * t4;
        float t5 = aq + Bj[(size_t)i5 * NH]; s5 += t5 * t5;
        float t6 = aq + Bj[(size_t)i6 * NH]; s6 += t6 * t6;
        float t7 = aq + Bj[(size_t)i7 * NH]; s7 += t7 * t7;
    }
    for (; e < e1; ++e) {
        float t = aq + Bj[(size_t)cidx(csr[e]) * NH];
        s0 += t * t;
    }
    float acc = ((s0 + s1) + (s2 + s3)) + ((s4 + s5) + (s6 + s7));
    out[(size_t)wid * NH + j] = tanhf(acc / fmaxf((float)(e1 - e0), 1.0f));
}

extern "C" void kernel_launch(void* const* d_in, const int* in_sizes, int n_in,
                              void* d_out, int out_size, void* d_ws, size_t ws_size,
                              hipStream_t stream) {
    const float* X      = (const float*)d_in[0];
    const int*   ei     = (const int*)d_in[1];   // [2, NE] int32
    const float* Wself  = (const float*)d_in[2];
    const float* Wneigh = (const float*)d_in[3];
    const float* bsage  = (const float*)d_in[4];
    const float* Qw     = (const float*)d_in[5];
    const float* Qb     = (const float*)d_in[6];
    const int* src = ei;
    const int* dst = ei + NE;

    float* out = (float*)d_out;

    // workspace layout (~44 MB)
    float* A = (float*)d_ws;                         // NN*NH floats
    float* B = A + (size_t)NN * NH;                  // NN*NH floats
    unsigned* pairs = (unsigned*)(B + (size_t)NN * NH); // NBKT*CAP u32
    int* csr   = (int*)(pairs + (size_t)NBKT * CAP); // 2*NE
    int* off   = csr + 2 * NE;                       // NKEY+1
    int* gcnt  = off + NKEY + 1;                     // NBKT
    int* gbase = gcnt + NBKT;                        // NBKT

    hipMemsetAsync(gcnt, 0, NBKT * sizeof(int), stream);

    bin_pass<<<512, 256, 0, stream>>>(src, dst, gcnt, pairs);
    bucket_scan<<<1, 256, 0, stream>>>(gcnt, gbase, off);
    sort_pass<<<NBKT, 1024, 0, stream>>>(pairs, gcnt, gbase, off, csr);
    gather_mean<<<(NN + 3) / 4, 256, 0, stream>>>(X, off + NN, csr, A);
    node_gemm<<<(NN + GNPB - 1) / GNPB, 128, 0, stream>>>(X, A, Wself, Wneigh,
                                                          bsage, Qw, B);
    edge_out<<<(NN + 3) / 4, 256, 0, stream>>>(A, B, Qb, off, csr, out);
}

// Round 12
// 169.954 us; speedup vs baseline: 1.0922x; 1.0579x over previous
//
#include <hip/hip_runtime.h>
#include <math.h>

#define NN 50000
#define NE 1000000
#define NH 64
#define NKEY 100000      // 2*NN combined key space (src | NN+dst)
#define SPAN 512         // keys per bucket
#define NBKT 196         // ceil(NKEY / SPAN)
#define CAP 12288        // bucket capacity (mean 10240, generous)
#define CH 32            // LDS staging entries per bucket (pow2 for shift math)
#define GNPB 64          // nodes per block in node_gemm
#define GLD 68           // padded leading dim for LDS tiles

// ---------- binning helpers -------------------------------------------------
__device__ __forceinline__ void push_pair(int key, int val, int* cnt,
                                          unsigned* buf, int* gcnt,
                                          unsigned* __restrict__ pairs) {
    int b = key >> 9;
    unsigned pk = ((unsigned)val << 9) | (unsigned)(key & 511);
    int slot = atomicAdd(&cnt[b], 1);           // LDS atomic
    if (slot < CH) {
        buf[b * CH + slot] = pk;
    } else {                                     // rare overflow: direct path
        int g = atomicAdd(&gcnt[b], 1);
        if (g < CAP) pairs[(size_t)b * CAP + g] = pk;
    }
}

// two-phase cooperative flush: parallel atomics, then flat coalesced copy
__device__ __forceinline__ void flush_coop(int* cnt, int* s_fc, int* s_g,
                                           unsigned* buf, int* gcnt,
                                           unsigned* __restrict__ pairs) {
    __syncthreads();
    int t = threadIdx.x;
    if (t < NBKT) {
        int fc = cnt[t]; if (fc > CH) fc = CH;
        s_fc[t] = fc;
        s_g[t] = (fc > 0) ? atomicAdd(&gcnt[t], fc) : 0;
    }
    __syncthreads();
    for (int i = t; i < NBKT * CH; i += 256) {
        int b = i >> 5, s = i & 31;              // CH == 32
        if (s < s_fc[b])
            pairs[(size_t)b * CAP + s_g[b] + s] = buf[i];
    }
    __syncthreads();
    if (t < NBKT) cnt[t] = 0;
    __syncthreads();
}

// ---------- pass 1: LDS-staged binning of 2M (key,val) pairs ----------------
__global__ __launch_bounds__(256) void bin_pass(
    const int* __restrict__ src, const int* __restrict__ dst,
    int* __restrict__ gcnt, unsigned* __restrict__ pairs) {
    __shared__ int cnt[NBKT];
    __shared__ int s_fc[NBKT];
    __shared__ int s_g[NBKT];
    __shared__ unsigned buf[NBKT * CH];
    for (int b = threadIdx.x; b < NBKT; b += 256) cnt[b] = 0;
    __syncthreads();
    int r = 0;
    for (int base = blockIdx.x * 256; base < NE; base += gridDim.x * 256) {
        int e = base + threadIdx.x;
        if (e < NE) {
            int s = src[e], d = dst[e];
            push_pair(s, d, cnt, buf, gcnt, pairs);       // out-edge of s
            push_pair(NN + d, s, cnt, buf, gcnt, pairs);  // in-edge of d
        }
        if ((++r & 7) == 0) flush_coop(cnt, s_fc, s_g, buf, gcnt, pairs);
    }
    flush_coop(cnt, s_fc, s_g, buf, gcnt, pairs);
}

// ---------- pass 2: per-bucket counting sort + off/csr (scan folded in) -----
__global__ __launch_bounds__(1024) void sort_pass(
    const unsigned* __restrict__ pairs, const int* __restrict__ gcnt,
    int* __restrict__ off, int* __restrict__ csr) {
    __shared__ int hist[SPAN];
    __shared__ int scn[SPAN];
    __shared__ int bsc[256];
    int k = blockIdx.x;
    int t = threadIdx.x;

    // local scan of all bucket counts -> this block's global base
    if (t < 256) bsc[t] = (t < NBKT) ? gcnt[t] : 0;
    __syncthreads();
    for (int o = 1; o < 256; o <<= 1) {
        int u = 0;
        if (t < 256 && t >= o) u = bsc[t - o];
        __syncthreads();
        if (t < 256) bsc[t] += u;
        __syncthreads();
    }
    int base = (k > 0) ? bsc[k - 1] : 0;
    int n = gcnt[k]; if (n > CAP) n = CAP;
    const unsigned* bp = pairs + (size_t)k * CAP;
    if (k == 0 && t == 0) off[NKEY] = 2 * NE;    // sentinel

    if (t < SPAN) hist[t] = 0;
    __syncthreads();
    for (int i = t; i < n; i += 1024)
        atomicAdd(&hist[bp[i] & 511], 1);
    __syncthreads();
    if (t < SPAN) scn[t] = hist[t];
    __syncthreads();
    for (int o = 1; o < SPAN; o <<= 1) {
        int u = 0;
        if (t < SPAN && t >= o) u = scn[t - o];
        __syncthreads();
        if (t < SPAN) scn[t] += u;
        __syncthreads();
    }
    if (t < SPAN) {
        int ex = base + scn[t] - hist[t];   // absolute exclusive prefix
        int gk = k * SPAN + t;
        if (gk < NKEY) off[gk] = ex;
        scn[t] = ex;                        // reuse as cursor
    }
    __syncthreads();
    for (int i = t; i < n; i += 1024) {
        unsigned p = bp[i];
        int pos = atomicAdd(&scn[p & 511], 1);   // LDS atomic
        csr[pos] = (int)(p >> 9);                // block-local global store
    }
}

// clamp gathered index (protects rocprof dispatch-replay from stale buffers;
// compiles to v_med3_i32, free in a latency-bound gather loop)
__device__ __forceinline__ int cidx(int i) {
    return max(0, min(i, NN - 1));
}

// ---------- pass 3: wave-per-node gather-mean, 8-deep ILP -------------------
__global__ __launch_bounds__(256) void gather_mean(
    const float* __restrict__ X, const int* __restrict__ off_dst,
    const int* __restrict__ csr, float* __restrict__ M) {
    int wid = (int)(((long long)blockIdx.x * blockDim.x + threadIdx.x) >> 6);
    int j = threadIdx.x & 63;
    if (wid >= NN) return;
    int e0 = off_dst[wid], e1 = off_dst[wid + 1];
    const float* Xj = X + j;
    float s0 = 0, s1 = 0, s2 = 0, s3 = 0, s4 = 0, s5 = 0, s6 = 0, s7 = 0;
    int e = e0;
    for (; e + 8 <= e1; e += 8) {
        int i0 = cidx(csr[e + 0]), i1 = cidx(csr[e + 1]);
        int i2 = cidx(csr[e + 2]), i3 = cidx(csr[e + 3]);
        int i4 = cidx(csr[e + 4]), i5 = cidx(csr[e + 5]);
        int i6 = cidx(csr[e + 6]), i7 = cidx(csr[e + 7]);
        s0 += Xj[(size_t)i0 * NH]; s1 += Xj[(size_t)i1 * NH];
        s2 += Xj[(size_t)i2 * NH]; s3 += Xj[(size_t)i3 * NH];
        s4 += Xj[(size_t)i4 * NH]; s5 += Xj[(size_t)i5 * NH];
        s6 += Xj[(size_t)i6 * NH]; s7 += Xj[(size_t)i7 * NH];
    }
    for (; e < e1; ++e) s0 += Xj[(size_t)cidx(csr[e]) * NH];
    float sum = ((s0 + s1) + (s2 + s3)) + ((s4 + s5) + (s6 + s7));
    M[(size_t)wid * NH + j] = sum / fmaxf((float)(e1 - e0), 1.0f);
}

// ---------- pass 4: node GEMM v5 (proven 43 us) — LDS-tiled, 64 nodes/block -
// 256 threads, 4x4 register tile. Two-stage weights: Ws/Wn for phase 1,
// Q1/Q2 re-staged into the same 32 KB for phase 2. LDS total 67 KB.
__global__ __launch_bounds__(256, 2) void node_gemm(
    const float* __restrict__ X, float* MA /* in: mean, out: A (aliased) */,
    const float* __restrict__ Wself, const float* __restrict__ Wneigh,
    const float* __restrict__ bsage, const float* __restrict__ Qw,
    float* __restrict__ B) {
    __shared__ __align__(16) float sWa[4096];       // Ws, then Q1  [k][j]
    __shared__ __align__(16) float sWb[4096];       // Wn, then Q2  [k][j]
    __shared__ __align__(16) float sx[GNPB * GLD];  // x [node][k]
    __shared__ __align__(16) float sh[GNPB * GLD];  // mean, then h [node][j]

    const int T  = threadIdx.x;
    const int tj = T & 15;          // cols 4*tj..4*tj+3
    const int tn = T >> 4;          // nodes 4*tn..4*tn+3 (tn 0..15)
    const int nbase = blockIdx.x * GNPB;

    // stage Ws, Wn (1024 float4 each)
    #pragma unroll
    for (int r = 0; r < 4; ++r) {
        int i = r * 256 + T;
        ((float4*)sWa)[i] = ((const float4*)Wself)[i];
        ((float4*)sWb)[i] = ((const float4*)Wneigh)[i];
    }
    // stage x, mean row-major (coalesced float4; 64 nodes x 16 float4)
    #pragma unroll
    for (int r = 0; r < 4; ++r) {
        int F = r * 256 + T;        // 0..1023
        int node = F >> 4;          // 0..63
        int k4 = F & 15;
        int gn = nbase + node; if (gn > NN - 1) gn = NN - 1;
        float4 xv = ((const float4*)&X[(size_t)gn * NH])[k4];
        float4 mv = ((const float4*)&MA[(size_t)gn * NH])[k4];
        *(float4*)&sx[node * GLD + k4 * 4] = xv;
        *(float4*)&sh[node * GLD + k4 * 4] = mv;
    }
    __syncthreads();

    // ---- phase 1: h = relu(x Ws + m Wn + b) ----
    float4 bv = ((const float4*)bsage)[tj];
    const float* bp = (const float*)&bv;
    float acc[4][4];
    #pragma unroll
    for (int ni = 0; ni < 4; ++ni)
        #pragma unroll
        for (int ji = 0; ji < 4; ++ji) acc[ni][ji] = bp[ji];

    for (int k0 = 0; k0 < 64; k0 += 4) {
        float4 xr[4], mr[4], wa[4], wb[4];
        #pragma unroll
        for (int ni = 0; ni < 4; ++ni) {
            xr[ni] = *(const float4*)&sx[(tn * 4 + ni) * GLD + k0];
            mr[ni] = *(const float4*)&sh[(tn * 4 + ni) * GLD + k0];
        }
        #pragma unroll
        for (int kk = 0; kk < 4; ++kk) {
            wa[kk] = ((const float4*)sWa)[(k0 + kk) * 16 + tj];
            wb[kk] = ((const float4*)sWb)[(k0 + kk) * 16 + tj];
        }
        #pragma unroll
        for (int ni = 0; ni < 4; ++ni)
            #pragma unroll
            for (int kk = 0; kk < 4; ++kk) {
                float xs = ((const float*)&xr[ni])[kk];
                float ms = ((const float*)&mr[ni])[kk];
                #pragma unroll
                for (int ji = 0; ji < 4; ++ji)
                    acc[ni][ji] += xs * ((const float*)&wa[kk])[ji]
                                 + ms * ((const float*)&wb[kk])[ji];
            }
    }
    __syncthreads();   // all sh(mean) + weight reads done

    // write h = relu(acc) into sh; re-stage Q1/Q2 over Ws/Wn
    #pragma unroll
    for (int ni = 0; ni < 4; ++ni) {
        float4 hv;
        hv.x = fmaxf(acc[ni][0], 0.0f);
        hv.y = fmaxf(acc[ni][1], 0.0f);
        hv.z = fmaxf(acc[ni][2], 0.0f);
        hv.w = fmaxf(acc[ni][3], 0.0f);
        *(float4*)&sh[(tn * 4 + ni) * GLD + tj * 4] = hv;
    }
    #pragma unroll
    for (int r = 0; r < 4; ++r) {
        int i = r * 256 + T;
        ((float4*)sWa)[i] = ((const float4*)Qw)[i];           // rows 0..63
        ((float4*)sWb)[i] = ((const float4*)(Qw + 4096))[i];  // rows 64..127
    }
    __syncthreads();

    // ---- phase 2: A = h Q1, B = h Q2 ----
    float aA[4][4], aB[4][4];
    #pragma unroll
    for (int ni = 0; ni < 4; ++ni)
        #pragma unroll
        for (int ji = 0; ji < 4; ++ji) { aA[ni][ji] = 0.0f; aB[ni][ji] = 0.0f; }

    for (int j0 = 0; j0 < 64; j0 += 4) {
        float4 hr[4], q1[4], q2[4];
        #pragma unroll
        for (int ni = 0; ni < 4; ++ni)
            hr[ni] = *(const float4*)&sh[(tn * 4 + ni) * GLD + j0];
        #pragma unroll
        for (int jj = 0; jj < 4; ++jj) {
            q1[jj] = ((const float4*)sWa)[(j0 + jj) * 16 + tj];
            q2[jj] = ((const float4*)sWb)[(j0 + jj) * 16 + tj];
        }
        #pragma unroll
        for (int ni = 0; ni < 4; ++ni)
            #pragma unroll
            for (int jj = 0; jj < 4; ++jj) {
                float hs = ((const float*)&hr[ni])[jj];
                #pragma unroll
                for (int ji = 0; ji < 4; ++ji) {
                    aA[ni][ji] += hs * ((const float*)&q1[jj])[ji];
                    aB[ni][ji] += hs * ((const float*)&q2[jj])[ji];
                }
            }
    }

    // store A (over mean) and B
    #pragma unroll
    for (int ni = 0; ni < 4; ++ni) {
        int gn = nbase + tn * 4 + ni;
        if (gn < NN) {
            float4 va, vb;
            va.x = aA[ni][0]; va.y = aA[ni][1]; va.z = aA[ni][2]; va.w = aA[ni][3];
            vb.x = aB[ni][0]; vb.y = aB[ni][1]; vb.z = aB[ni][2]; vb.w = aB[ni][3];
            *(float4*)&MA[(size_t)gn * NH + tj * 4] = va;
            *(float4*)&B[(size_t)gn * NH + tj * 4] = vb;
        }
    }
}

// ---------- pass 5: wave-per-node out-edge reduction, 8-deep ILP ------------
__global__ __launch_bounds__(256) void edge_out(
    const float* __restrict__ A, const float* __restrict__ B,
    const float* __restrict__ Qb, const int* __restrict__ off_src,
    const int* __restrict__ csr, float* __restrict__ out) {
    int wid = (int)(((long long)blockIdx.x * blockDim.x + threadIdx.x) >> 6);
    int j = threadIdx.x & 63;
    if (wid >= NN) return;
    float aq = A[(size_t)wid * NH + j] + Qb[j];
    int e0 = off_src[wid], e1 = off_src[wid + 1];
    const float* Bj = B + j;
    float s0 = 0, s1 = 0, s2 = 0, s3 = 0, s4 = 0, s5 = 0, s6 = 0, s7 = 0;
    int e = e0;
    for (; e + 8 <= e1; e += 8) {
        int i0 = cidx(csr[e + 0]), i1 = cidx(csr[e + 1]);
        int i2 = cidx(csr[e + 2]), i3 = cidx(csr[e + 3]);
        int i4 = cidx(csr[e + 4]), i5 = cidx(csr[e + 5]);
        int i6 = cidx(csr[e + 6]), i7 = cidx(csr[e + 7]);
        float t0 = aq + Bj[(size_t)i0 * NH]; s0 += t0 * t0;
        float t1 = aq + Bj[(size_t)i1 * NH]; s1 += t1 * t1;
        float t2 = aq + Bj[(size_t)i2 * NH]; s2 += t2 * t2;
        float t3 = aq + Bj[(size_t)i3 * NH]; s3 += t3 * t3;
        float t4 = aq + Bj[(size_t)i4 * NH]; s4 += t4 * t4;
        float t5 = aq + Bj[(size_t)i5 * NH]; s5 += t5 * t5;
        float t6 = aq + Bj[(size_t)i6 * NH]; s6 += t6 * t6;
        float t7 = aq + Bj[(size_t)i7 * NH]; s7 += t7 * t7;
    }
    for (; e < e1; ++e) {
        float t = aq + Bj[(size_t)cidx(csr[e]) * NH];
        s0 += t * t;
    }
    float acc = ((s0 + s1) + (s2 + s3)) + ((s4 + s5) + (s6 + s7));
    out[(size_t)wid * NH + j] = tanhf(acc / fmaxf((float)(e1 - e0), 1.0f));
}

extern "C" void kernel_launch(void* const* d_in, const int* in_sizes, int n_in,
                              void* d_out, int out_size, void* d_ws, size_t ws_size,
                              hipStream_t stream) {
    const float* X      = (const float*)d_in[0];
    const int*   ei     = (const int*)d_in[1];   // [2, NE] int32
    const float* Wself  = (const float*)d_in[2];
    const float* Wneigh = (const float*)d_in[3];
    const float* bsage  = (const float*)d_in[4];
    const float* Qw     = (const float*)d_in[5];
    const float* Qb     = (const float*)d_in[6];
    const int* src = ei;
    const int* dst = ei + NE;

    float* out = (float*)d_out;

    // workspace layout (~44 MB)
    float* A = (float*)d_ws;                         // NN*NH floats
    float* B = A + (size_t)NN * NH;                  // NN*NH floats
    unsigned* pairs = (unsigned*)(B + (size_t)NN * NH); // NBKT*CAP u32
    int* csr   = (int*)(pairs + (size_t)NBKT * CAP); // 2*NE
    int* off   = csr + 2 * NE;                       // NKEY+1
    int* gcnt  = off + NKEY + 1;                     // NBKT

    hipMemsetAsync(gcnt, 0, NBKT * sizeof(int), stream);

    bin_pass<<<512, 256, 0, stream>>>(src, dst, gcnt, pairs);
    sort_pass<<<NBKT, 1024, 0, stream>>>(pairs, gcnt, off, csr);
    gather_mean<<<(NN + 3) / 4, 256, 0, stream>>>(X, off + NN, csr, A);
    node_gemm<<<(NN + GNPB - 1) / GNPB, 256, 0, stream>>>(X, A, Wself, Wneigh,
                                                          bsage, Qw, B);
    edge_out<<<(NN + 3) / 4, 256, 0, stream>>>(A, B, Qb, off, csr, out);
}

// Round 13
// 164.828 us; speedup vs baseline: 1.1262x; 1.0311x over previous
//
#include <hip/hip_runtime.h>
#include <math.h>

#define NN 50000
#define NE 1000000
#define NH 64
#define NKEY 100000      // 2*NN combined key space (src | NN+dst)
#define SPAN 512         // keys per bucket
#define NBKT 196         // ceil(NKEY / SPAN)
#define CAP 12288        // bucket capacity (mean 10240, generous)
#define CH 32            // LDS staging entries per bucket (pow2 for shift math)
#define GNPB 64          // nodes per block in node_gemm
#define GLD 68           // padded leading dim for LDS tiles

typedef unsigned short u16;

__device__ __forceinline__ u16 f2bf(float f) {   // round-to-nearest-even
    unsigned u = __float_as_uint(f);
    return (u16)((u + 0x7FFFu + ((u >> 16) & 1u)) >> 16);
}
__device__ __forceinline__ float bf2f(u16 h) {
    return __uint_as_float((unsigned)h << 16);
}

// ---------- pass 0: X -> bf16 table ----------------------------------------
__global__ __launch_bounds__(256) void convert_x(
    const float* __restrict__ X, u16* __restrict__ X16) {
    int i = blockIdx.x * 256 + threadIdx.x;
    if (i >= NN * NH / 4) return;
    float4 v = ((const float4*)X)[i];
    ushort4 o;
    o.x = f2bf(v.x); o.y = f2bf(v.y); o.z = f2bf(v.z); o.w = f2bf(v.w);
    ((ushort4*)X16)[i] = o;
}

// ---------- binning helpers -------------------------------------------------
__device__ __forceinline__ void push_pair(int key, int val, int* cnt,
                                          unsigned* buf, int* gcnt,
                                          unsigned* __restrict__ pairs) {
    int b = key >> 9;
    unsigned pk = ((unsigned)val << 9) | (unsigned)(key & 511);
    int slot = atomicAdd(&cnt[b], 1);           // LDS atomic
    if (slot < CH) {
        buf[b * CH + slot] = pk;
    } else {                                     // rare overflow: direct path
        int g = atomicAdd(&gcnt[b], 1);
        if (g < CAP) pairs[(size_t)b * CAP + g] = pk;
    }
}

// two-phase cooperative flush: parallel atomics, then flat coalesced copy
__device__ __forceinline__ void flush_coop(int* cnt, int* s_fc, int* s_g,
                                           unsigned* buf, int* gcnt,
                                           unsigned* __restrict__ pairs) {
    __syncthreads();
    int t = threadIdx.x;
    if (t < NBKT) {
        int fc = cnt[t]; if (fc > CH) fc = CH;
        s_fc[t] = fc;
        s_g[t] = (fc > 0) ? atomicAdd(&gcnt[t], fc) : 0;
    }
    __syncthreads();
    for (int i = t; i < NBKT * CH; i += 256) {
        int b = i >> 5, s = i & 31;              // CH == 32
        if (s < s_fc[b])
            pairs[(size_t)b * CAP + s_g[b] + s] = buf[i];
    }
    __syncthreads();
    if (t < NBKT) cnt[t] = 0;
    __syncthreads();
}

// ---------- pass 1: LDS-staged binning of 2M (key,val) pairs ----------------
__global__ __launch_bounds__(256) void bin_pass(
    const int* __restrict__ src, const int* __restrict__ dst,
    int* __restrict__ gcnt, unsigned* __restrict__ pairs) {
    __shared__ int cnt[NBKT];
    __shared__ int s_fc[NBKT];
    __shared__ int s_g[NBKT];
    __shared__ unsigned buf[NBKT * CH];
    for (int b = threadIdx.x; b < NBKT; b += 256) cnt[b] = 0;
    __syncthreads();
    int r = 0;
    for (int base = blockIdx.x * 256; base < NE; base += gridDim.x * 256) {
        int e = base + threadIdx.x;
        if (e < NE) {
            int s = src[e], d = dst[e];
            push_pair(s, d, cnt, buf, gcnt, pairs);       // out-edge of s
            push_pair(NN + d, s, cnt, buf, gcnt, pairs);  // in-edge of d
        }
        if ((++r & 7) == 0) flush_coop(cnt, s_fc, s_g, buf, gcnt, pairs);
    }
    flush_coop(cnt, s_fc, s_g, buf, gcnt, pairs);
}

// ---------- pass 2: per-bucket counting sort + off/csr (scan folded in) -----
__global__ __launch_bounds__(1024) void sort_pass(
    const unsigned* __restrict__ pairs, const int* __restrict__ gcnt,
    int* __restrict__ off, int* __restrict__ csr) {
    __shared__ int hist[SPAN];
    __shared__ int scn[SPAN];
    __shared__ int bsc[256];
    int k = blockIdx.x;
    int t = threadIdx.x;

    // local scan of all bucket counts -> this block's global base
    if (t < 256) bsc[t] = (t < NBKT) ? gcnt[t] : 0;
    __syncthreads();
    for (int o = 1; o < 256; o <<= 1) {
        int u = 0;
        if (t < 256 && t >= o) u = bsc[t - o];
        __syncthreads();
        if (t < 256) bsc[t] += u;
        __syncthreads();
    }
    int base = (k > 0) ? bsc[k - 1] : 0;
    int n = gcnt[k]; if (n > CAP) n = CAP;
    const unsigned* bp = pairs + (size_t)k * CAP;
    if (k == 0 && t == 0) off[NKEY] = 2 * NE;    // sentinel

    if (t < SPAN) hist[t] = 0;
    __syncthreads();
    for (int i = t; i < n; i += 1024)
        atomicAdd(&hist[bp[i] & 511], 1);
    __syncthreads();
    if (t < SPAN) scn[t] = hist[t];
    __syncthreads();
    for (int o = 1; o < SPAN; o <<= 1) {
        int u = 0;
        if (t < SPAN && t >= o) u = scn[t - o];
        __syncthreads();
        if (t < SPAN) scn[t] += u;
        __syncthreads();
    }
    if (t < SPAN) {
        int ex = base + scn[t] - hist[t];   // absolute exclusive prefix
        int gk = k * SPAN + t;
        if (gk < NKEY) off[gk] = ex;
        scn[t] = ex;                        // reuse as cursor
    }
    __syncthreads();
    for (int i = t; i < n; i += 1024) {
        unsigned p = bp[i];
        int pos = atomicAdd(&scn[p & 511], 1);   // LDS atomic
        csr[pos] = (int)(p >> 9);                // block-local global store
    }
}

// clamp gathered index (protects rocprof dispatch-replay from stale buffers;
// compiles to v_med3_i32, free in a latency-bound gather loop)
__device__ __forceinline__ int cidx(int i) {
    return max(0, min(i, NN - 1));
}

// ---------- pass 3: wave-per-node gather-mean (bf16 rows), 8-deep ILP -------
__global__ __launch_bounds__(256) void gather_mean(
    const u16* __restrict__ X16, const int* __restrict__ off_dst,
    const int* __restrict__ csr, float* __restrict__ M) {
    int wid = (int)(((long long)blockIdx.x * blockDim.x + threadIdx.x) >> 6);
    int j = threadIdx.x & 63;
    if (wid >= NN) return;
    int e0 = off_dst[wid], e1 = off_dst[wid + 1];
    const u16* Xj = X16 + j;
    float s0 = 0, s1 = 0, s2 = 0, s3 = 0, s4 = 0, s5 = 0, s6 = 0, s7 = 0;
    int e = e0;
    for (; e + 8 <= e1; e += 8) {
        int i0 = cidx(csr[e + 0]), i1 = cidx(csr[e + 1]);
        int i2 = cidx(csr[e + 2]), i3 = cidx(csr[e + 3]);
        int i4 = cidx(csr[e + 4]), i5 = cidx(csr[e + 5]);
        int i6 = cidx(csr[e + 6]), i7 = cidx(csr[e + 7]);
        s0 += bf2f(Xj[(size_t)i0 * NH]); s1 += bf2f(Xj[(size_t)i1 * NH]);
        s2 += bf2f(Xj[(size_t)i2 * NH]); s3 += bf2f(Xj[(size_t)i3 * NH]);
        s4 += bf2f(Xj[(size_t)i4 * NH]); s5 += bf2f(Xj[(size_t)i5 * NH]);
        s6 += bf2f(Xj[(size_t)i6 * NH]); s7 += bf2f(Xj[(size_t)i7 * NH]);
    }
    for (; e < e1; ++e) s0 += bf2f(Xj[(size_t)cidx(csr[e]) * NH]);
    float sum = ((s0 + s1) + (s2 + s3)) + ((s4 + s5) + (s6 + s7));
    M[(size_t)wid * NH + j] = sum / fmaxf((float)(e1 - e0), 1.0f);
}

// ---------- pass 4: node GEMM v5 — LDS-tiled, 64 nodes/block, 2 blocks/CU ---
// 256 threads, 4x4 register tile. Two-stage weights: Ws/Wn for phase 1,
// Q1/Q2 re-staged into the same 32 KB for phase 2. B emitted as bf16.
__global__ __launch_bounds__(256, 2) void node_gemm(
    const float* __restrict__ X, float* MA /* in: mean, out: A (aliased) */,
    const float* __restrict__ Wself, const float* __restrict__ Wneigh,
    const float* __restrict__ bsage, const float* __restrict__ Qw,
    u16* __restrict__ B16) {
    __shared__ __align__(16) float sWa[4096];       // Ws, then Q1  [k][j]
    __shared__ __align__(16) float sWb[4096];       // Wn, then Q2  [k][j]
    __shared__ __align__(16) float sx[GNPB * GLD];  // x [node][k]
    __shared__ __align__(16) float sh[GNPB * GLD];  // mean, then h [node][j]

    const int T  = threadIdx.x;
    const int tj = T & 15;          // cols 4*tj..4*tj+3
    const int tn = T >> 4;          // nodes 4*tn..4*tn+3 (tn 0..15)
    const int nbase = blockIdx.x * GNPB;

    // stage Ws, Wn (1024 float4 each)
    #pragma unroll
    for (int r = 0; r < 4; ++r) {
        int i = r * 256 + T;
        ((float4*)sWa)[i] = ((const float4*)Wself)[i];
        ((float4*)sWb)[i] = ((const float4*)Wneigh)[i];
    }
    // stage x, mean row-major (coalesced float4; 64 nodes x 16 float4)
    #pragma unroll
    for (int r = 0; r < 4; ++r) {
        int F = r * 256 + T;        // 0..1023
        int node = F >> 4;          // 0..63
        int k4 = F & 15;
        int gn = nbase + node; if (gn > NN - 1) gn = NN - 1;
        float4 xv = ((const float4*)&X[(size_t)gn * NH])[k4];
        float4 mv = ((const float4*)&MA[(size_t)gn * NH])[k4];
        *(float4*)&sx[node * GLD + k4 * 4] = xv;
        *(float4*)&sh[node * GLD + k4 * 4] = mv;
    }
    __syncthreads();

    // ---- phase 1: h = relu(x Ws + m Wn + b) ----
    float4 bv = ((const float4*)bsage)[tj];
    const float* bp = (const float*)&bv;
    float acc[4][4];
    #pragma unroll
    for (int ni = 0; ni < 4; ++ni)
        #pragma unroll
        for (int ji = 0; ji < 4; ++ji) acc[ni][ji] = bp[ji];

    for (int k0 = 0; k0 < 64; k0 += 4) {
        float4 xr[4], mr[4], wa[4], wb[4];
        #pragma unroll
        for (int ni = 0; ni < 4; ++ni) {
            xr[ni] = *(const float4*)&sx[(tn * 4 + ni) * GLD + k0];
            mr[ni] = *(const float4*)&sh[(tn * 4 + ni) * GLD + k0];
        }
        #pragma unroll
        for (int kk = 0; kk < 4; ++kk) {
            wa[kk] = ((const float4*)sWa)[(k0 + kk) * 16 + tj];
            wb[kk] = ((const float4*)sWb)[(k0 + kk) * 16 + tj];
        }
        #pragma unroll
        for (int ni = 0; ni < 4; ++ni)
            #pragma unroll
            for (int kk = 0; kk < 4; ++kk) {
                float xs = ((const float*)&xr[ni])[kk];
                float ms = ((const float*)&mr[ni])[kk];
                #pragma unroll
                for (int ji = 0; ji < 4; ++ji)
                    acc[ni][ji] += xs * ((const float*)&wa[kk])[ji]
                                 + ms * ((const float*)&wb[kk])[ji];
            }
    }
    __syncthreads();   // all sh(mean) + weight reads done

    // write h = relu(acc) into sh; re-stage Q1/Q2 over Ws/Wn
    #pragma unroll
    for (int ni = 0; ni < 4; ++ni) {
        float4 hv;
        hv.x = fmaxf(acc[ni][0], 0.0f);
        hv.y = fmaxf(acc[ni][1], 0.0f);
        hv.z = fmaxf(acc[ni][2], 0.0f);
        hv.w = fmaxf(acc[ni][3], 0.0f);
        *(float4*)&sh[(tn * 4 + ni) * GLD + tj * 4] = hv;
    }
    #pragma unroll
    for (int r = 0; r < 4; ++r) {
        int i = r * 256 + T;
        ((float4*)sWa)[i] = ((const float4*)Qw)[i];           // rows 0..63
        ((float4*)sWb)[i] = ((const float4*)(Qw + 4096))[i];  // rows 64..127
    }
    __syncthreads();

    // ---- phase 2: A = h Q1, B = h Q2 ----
    float aA[4][4], aB[4][4];
    #pragma unroll
    for (int ni = 0; ni < 4; ++ni)
        #pragma unroll
        for (int ji = 0; ji < 4; ++ji) { aA[ni][ji] = 0.0f; aB[ni][ji] = 0.0f; }

    for (int j0 = 0; j0 < 64; j0 += 4) {
        float4 hr[4], q1[4], q2[4];
        #pragma unroll
        for (int ni = 0; ni < 4; ++ni)
            hr[ni] = *(const float4*)&sh[(tn * 4 + ni) * GLD + j0];
        #pragma unroll
        for (int jj = 0; jj < 4; ++jj) {
            q1[jj] = ((const float4*)sWa)[(j0 + jj) * 16 + tj];
            q2[jj] = ((const float4*)sWb)[(j0 + jj) * 16 + tj];
        }
        #pragma unroll
        for (int ni = 0; ni < 4; ++ni)
            #pragma unroll
            for (int jj = 0; jj < 4; ++jj) {
                float hs = ((const float*)&hr[ni])[jj];
                #pragma unroll
                for (int ji = 0; ji < 4; ++ji) {
                    aA[ni][ji] += hs * ((const float*)&q1[jj])[ji];
                    aB[ni][ji] += hs * ((const float*)&q2[jj])[ji];
                }
            }
    }

    // store A (f32, over mean) and B (bf16)
    #pragma unroll
    for (int ni = 0; ni < 4; ++ni) {
        int gn = nbase + tn * 4 + ni;
        if (gn < NN) {
            float4 va;
            va.x = aA[ni][0]; va.y = aA[ni][1]; va.z = aA[ni][2]; va.w = aA[ni][3];
            *(float4*)&MA[(size_t)gn * NH + tj * 4] = va;
            ushort4 vb;
            vb.x = f2bf(aB[ni][0]); vb.y = f2bf(aB[ni][1]);
            vb.z = f2bf(aB[ni][2]); vb.w = f2bf(aB[ni][3]);
            *(ushort4*)&B16[(size_t)gn * NH + tj * 4] = vb;
        }
    }
}

// ---------- pass 5: wave-per-node out-edge reduction (bf16 B), 8-deep ILP ---
__global__ __launch_bounds__(256) void edge_out(
    const float* __restrict__ A, const u16* __restrict__ B16,
    const float* __restrict__ Qb, const int* __restrict__ off_src,
    const int* __restrict__ csr, float* __restrict__ out) {
    int wid = (int)(((long long)blockIdx.x * blockDim.x + threadIdx.x) >> 6);
    int j = threadIdx.x & 63;
    if (wid >= NN) return;
    float aq = A[(size_t)wid * NH + j] + Qb[j];
    int e0 = off_src[wid], e1 = off_src[wid + 1];
    const u16* Bj = B16 + j;
    float s0 = 0, s1 = 0, s2 = 0, s3 = 0, s4 = 0, s5 = 0, s6 = 0, s7 = 0;
    int e = e0;
    for (; e + 8 <= e1; e += 8) {
        int i0 = cidx(csr[e + 0]), i1 = cidx(csr[e + 1]);
        int i2 = cidx(csr[e + 2]), i3 = cidx(csr[e + 3]);
        int i4 = cidx(csr[e + 4]), i5 = cidx(csr[e + 5]);
        int i6 = cidx(csr[e + 6]), i7 = cidx(csr[e + 7]);
        float t0 = aq + bf2f(Bj[(size_t)i0 * NH]); s0 += t0 * t0;
        float t1 = aq + bf2f(Bj[(size_t)i1 * NH]); s1 += t1 * t1;
        float t2 = aq + bf2f(Bj[(size_t)i2 * NH]); s2 += t2 * t2;
        float t3 = aq + bf2f(Bj[(size_t)i3 * NH]); s3 += t3 * t3;
        float t4 = aq + bf2f(Bj[(size_t)i4 * NH]); s4 += t4 * t4;
        float t5 = aq + bf2f(Bj[(size_t)i5 * NH]); s5 += t5 * t5;
        float t6 = aq + bf2f(Bj[(size_t)i6 * NH]); s6 += t6 * t6;
        float t7 = aq + bf2f(Bj[(size_t)i7 * NH]); s7 += t7 * t7;
    }
    for (; e < e1; ++e) {
        float t = aq + bf2f(Bj[(size_t)cidx(csr[e]) * NH]);
        s0 += t * t;
    }
    float acc = ((s0 + s1) + (s2 + s3)) + ((s4 + s5) + (s6 + s7));
    out[(size_t)wid * NH + j] = tanhf(acc / fmaxf((float)(e1 - e0), 1.0f));
}

extern "C" void kernel_launch(void* const* d_in, const int* in_sizes, int n_in,
                              void* d_out, int out_size, void* d_ws, size_t ws_size,
                              hipStream_t stream) {
    const float* X      = (const float*)d_in[0];
    const int*   ei     = (const int*)d_in[1];   // [2, NE] int32
    const float* Wself  = (const float*)d_in[2];
    const float* Wneigh = (const float*)d_in[3];
    const float* bsage  = (const float*)d_in[4];
    const float* Qw     = (const float*)d_in[5];
    const float* Qb     = (const float*)d_in[6];
    const int* src = ei;
    const int* dst = ei + NE;

    float* out = (float*)d_out;

    // workspace layout (~44 MB, unchanged from round 12)
    float* A   = (float*)d_ws;                       // NN*NH f32 (mean, then A)
    u16* X16   = (u16*)(A + (size_t)NN * NH);        // NN*NH bf16
    u16* B16   = X16 + (size_t)NN * NH;              // NN*NH bf16
    unsigned* pairs = (unsigned*)(B16 + (size_t)NN * NH); // NBKT*CAP u32
    int* csr   = (int*)(pairs + (size_t)NBKT * CAP); // 2*NE
    int* off   = csr + 2 * NE;                       // NKEY+1
    int* gcnt  = off + NKEY + 1;                     // NBKT

    hipMemsetAsync(gcnt, 0, NBKT * sizeof(int), stream);

    convert_x<<<(NN * NH / 4 + 255) / 256, 256, 0, stream>>>(X, X16);
    bin_pass<<<512, 256, 0, stream>>>(src, dst, gcnt, pairs);
    sort_pass<<<NBKT, 1024, 0, stream>>>(pairs, gcnt, off, csr);
    gather_mean<<<(NN + 3) / 4, 256, 0, stream>>>(X16, off + NN, csr, A);
    node_gemm<<<(NN + GNPB - 1) / GNPB, 256, 0, stream>>>(X, A, Wself, Wneigh,
                                                          bsage, Qw, B16);
    edge_out<<<(NN + 3) / 4, 256, 0, stream>>>(A, B16, Qb, off, csr, out);
}

// Round 14
// 144.587 us; speedup vs baseline: 1.2838x; 1.1400x over previous
//
#include <hip/hip_runtime.h>
#include <math.h>

#define NN 50000
#define NE 1000000
#define NH 64
#define NKEY 100000      // 2*NN combined key space (src | NN+dst)
#define SPAN 512         // keys per bucket
#define NBKT 196         // ceil(NKEY / SPAN)
#define CAP 12288        // bucket capacity (mean 10240, generous)
#define CH 32            // LDS staging entries per bucket (pow2 for shift math)

typedef _Float16 f16;
typedef _Float16 f16x4 __attribute__((ext_vector_type(4)));
typedef _Float16 f16x8 __attribute__((ext_vector_type(8)));
typedef float f32x4 __attribute__((ext_vector_type(4)));

// ---------- pass 0a: X -> f16 table -----------------------------------------
__global__ __launch_bounds__(256) void convert_x(
    const float* __restrict__ X, f16* __restrict__ X16) {
    int i = blockIdx.x * 256 + threadIdx.x;
    if (i >= NN * NH / 4) return;
    float4 v = ((const float4*)X)[i];
    f16x4 o = {(f16)v.x, (f16)v.y, (f16)v.z, (f16)v.w};
    ((f16x4*)X16)[i] = o;
}

// ---------- pass 0b: weights -> f16 fragment-packed -------------------------
// layout: wp[(((m*2+kc)*4+ct)*64+l)*8+e] = W_m[(kc*32+(l>>4)*8+e)*64 + ct*16+(l&15)]
// m: 0=Wself 1=Wneigh 2=Qw[0:64] 3=Qw[64:128]; A/B frag = 8 contiguous k per lane
__global__ __launch_bounds__(256) void pack_w(
    const float* __restrict__ Ws, const float* __restrict__ Wn,
    const float* __restrict__ Qw, f16* __restrict__ wp) {
    int o = blockIdx.x * 256 + threadIdx.x;   // 0..16383
    if (o >= 16384) return;
    int m  = o >> 12;
    int kc = (o >> 11) & 1;
    int l  = (o >> 3) & 63;
    int e  = o & 7;
    int ct = (o >> 9) & 3;
    int k  = kc * 32 + (l >> 4) * 8 + e;
    int j  = ct * 16 + (l & 15);
    const float* W = (m == 0) ? Ws : (m == 1) ? Wn : (m == 2) ? Qw : (Qw + 4096);
    wp[o] = (f16)W[k * 64 + j];
}

// ---------- binning helpers -------------------------------------------------
__device__ __forceinline__ void push_pair(int key, int val, int* cnt,
                                          unsigned* buf, int* gcnt,
                                          unsigned* __restrict__ pairs) {
    int b = key >> 9;
    unsigned pk = ((unsigned)val << 9) | (unsigned)(key & 511);
    int slot = atomicAdd(&cnt[b], 1);           // LDS atomic
    if (slot < CH) {
        buf[b * CH + slot] = pk;
    } else {                                     // rare overflow: direct path
        int g = atomicAdd(&gcnt[b], 1);
        if (g < CAP) pairs[(size_t)b * CAP + g] = pk;
    }
}

__device__ __forceinline__ void flush_coop(int* cnt, int* s_fc, int* s_g,
                                           unsigned* buf, int* gcnt,
                                           unsigned* __restrict__ pairs) {
    __syncthreads();
    int t = threadIdx.x;
    if (t < NBKT) {
        int fc = cnt[t]; if (fc > CH) fc = CH;
        s_fc[t] = fc;
        s_g[t] = (fc > 0) ? atomicAdd(&gcnt[t], fc) : 0;
    }
    __syncthreads();
    for (int i = t; i < NBKT * CH; i += 256) {
        int b = i >> 5, s = i & 31;              // CH == 32
        if (s < s_fc[b])
            pairs[(size_t)b * CAP + s_g[b] + s] = buf[i];
    }
    __syncthreads();
    if (t < NBKT) cnt[t] = 0;
    __syncthreads();
}

// ---------- pass 1: LDS-staged binning of 2M (key,val) pairs ----------------
__global__ __launch_bounds__(256) void bin_pass(
    const int* __restrict__ src, const int* __restrict__ dst,
    int* __restrict__ gcnt, unsigned* __restrict__ pairs) {
    __shared__ int cnt[NBKT];
    __shared__ int s_fc[NBKT];
    __shared__ int s_g[NBKT];
    __shared__ unsigned buf[NBKT * CH];
    for (int b = threadIdx.x; b < NBKT; b += 256) cnt[b] = 0;
    __syncthreads();
    int r = 0;
    for (int base = blockIdx.x * 256; base < NE; base += gridDim.x * 256) {
        int e = base + threadIdx.x;
        if (e < NE) {
            int s = src[e], d = dst[e];
            push_pair(s, d, cnt, buf, gcnt, pairs);       // out-edge of s
            push_pair(NN + d, s, cnt, buf, gcnt, pairs);  // in-edge of d
        }
        if ((++r & 7) == 0) flush_coop(cnt, s_fc, s_g, buf, gcnt, pairs);
    }
    flush_coop(cnt, s_fc, s_g, buf, gcnt, pairs);
}

// ---------- pass 2: per-bucket counting sort + off/csr (scan folded in) -----
__global__ __launch_bounds__(1024) void sort_pass(
    const unsigned* __restrict__ pairs, const int* __restrict__ gcnt,
    int* __restrict__ off, int* __restrict__ csr) {
    __shared__ int hist[SPAN];
    __shared__ int scn[SPAN];
    __shared__ int bsc[256];
    int k = blockIdx.x;
    int t = threadIdx.x;

    if (t < 256) bsc[t] = (t < NBKT) ? gcnt[t] : 0;
    __syncthreads();
    for (int o = 1; o < 256; o <<= 1) {
        int u = 0;
        if (t < 256 && t >= o) u = bsc[t - o];
        __syncthreads();
        if (t < 256) bsc[t] += u;
        __syncthreads();
    }
    int base = (k > 0) ? bsc[k - 1] : 0;
    int n = gcnt[k]; if (n > CAP) n = CAP;
    const unsigned* bp = pairs + (size_t)k * CAP;
    if (k == 0 && t == 0) off[NKEY] = 2 * NE;    // sentinel

    if (t < SPAN) hist[t] = 0;
    __syncthreads();
    for (int i = t; i < n; i += 1024)
        atomicAdd(&hist[bp[i] & 511], 1);
    __syncthreads();
    if (t < SPAN) scn[t] = hist[t];
    __syncthreads();
    for (int o = 1; o < SPAN; o <<= 1) {
        int u = 0;
        if (t < SPAN && t >= o) u = scn[t - o];
        __syncthreads();
        if (t < SPAN) scn[t] += u;
        __syncthreads();
    }
    if (t < SPAN) {
        int ex = base + scn[t] - hist[t];   // absolute exclusive prefix
        int gk = k * SPAN + t;
        if (gk < NKEY) off[gk] = ex;
        scn[t] = ex;                        // reuse as cursor
    }
    __syncthreads();
    for (int i = t; i < n; i += 1024) {
        unsigned p = bp[i];
        int pos = atomicAdd(&scn[p & 511], 1);   // LDS atomic
        csr[pos] = (int)(p >> 9);                // block-local global store
    }
}

// clamp gathered index (protects rocprof dispatch-replay from stale buffers)
__device__ __forceinline__ int cidx(int i) {
    return max(0, min(i, NN - 1));
}

// ---------- pass 3: wave-per-node gather-mean (f16 rows), 8-deep ILP --------
__global__ __launch_bounds__(256) void gather_mean(
    const f16* __restrict__ X16, const int* __restrict__ off_dst,
    const int* __restrict__ csr, f16* __restrict__ M16) {
    int wid = (int)(((long long)blockIdx.x * blockDim.x + threadIdx.x) >> 6);
    int j = threadIdx.x & 63;
    if (wid >= NN) return;
    int e0 = off_dst[wid], e1 = off_dst[wid + 1];
    const f16* Xj = X16 + j;
    float s0 = 0, s1 = 0, s2 = 0, s3 = 0, s4 = 0, s5 = 0, s6 = 0, s7 = 0;
    int e = e0;
    for (; e + 8 <= e1; e += 8) {
        int i0 = cidx(csr[e + 0]), i1 = cidx(csr[e + 1]);
        int i2 = cidx(csr[e + 2]), i3 = cidx(csr[e + 3]);
        int i4 = cidx(csr[e + 4]), i5 = cidx(csr[e + 5]);
        int i6 = cidx(csr[e + 6]), i7 = cidx(csr[e + 7]);
        s0 += (float)Xj[(size_t)i0 * NH]; s1 += (float)Xj[(size_t)i1 * NH];
        s2 += (float)Xj[(size_t)i2 * NH]; s3 += (float)Xj[(size_t)i3 * NH];
        s4 += (float)Xj[(size_t)i4 * NH]; s5 += (float)Xj[(size_t)i5 * NH];
        s6 += (float)Xj[(size_t)i6 * NH]; s7 += (float)Xj[(size_t)i7 * NH];
    }
    for (; e < e1; ++e) s0 += (float)Xj[(size_t)cidx(csr[e]) * NH];
    float sum = ((s0 + s1) + (s2 + s3)) + ((s4 + s5) + (s6 + s7));
    M16[(size_t)wid * NH + j] = (f16)(sum / fmaxf((float)(e1 - e0), 1.0f));
}

// ---------- pass 4: node GEMM v8 — MFMA f16 ---------------------------------
// 256 thr = 4 waves, 64 nodes/block. Wave w owns rows 16w..16w+15.
// A-frags (X/M/H): lane l holds row (l&15), k = 8*(l>>4)..+7 (one b128).
// B-frags (weights): pre-packed by pack_w, coalesced b128 loads, L2-resident.
// D: row = 4*(l>>4)+i, col = (l&15)+16ct  [m89-verified layout].
// H round-trips through 8 KB LDS with chunk-XOR swizzle (conflict-free reads).
__global__ __launch_bounds__(256) void node_gemm(
    const f16* __restrict__ X16, const f16* __restrict__ M16,
    const f16* __restrict__ wp, const float* __restrict__ bsage,
    float* __restrict__ A, f16* __restrict__ B16) {
    __shared__ f16 H16[64 * 64];
    const int T = threadIdx.x;
    const int l = T & 63, w = T >> 6;
    const int lr = l & 15, lg = l >> 4;
    const int nbase = blockIdx.x * 64;
    const int arow = w * 16 + lr;                 // A-frag row (block-local)
    const int node = min(nbase + arow, NN - 1);
    const int kb = lg * 8;

    const f16x8* wv = (const f16x8*)wp;
    f16x8 xa0 = *(const f16x8*)&X16[(size_t)node * 64 + kb];
    f16x8 xa1 = *(const f16x8*)&X16[(size_t)node * 64 + 32 + kb];
    f16x8 ma0 = *(const f16x8*)&M16[(size_t)node * 64 + kb];
    f16x8 ma1 = *(const f16x8*)&M16[(size_t)node * 64 + 32 + kb];

    // ---- phase 1: H = relu(X Ws + M Wn + b) ----
    #pragma unroll
    for (int ct = 0; ct < 4; ++ct) {
        f16x8 ws0 = wv[(0 + ct) * 64 + l];        // Ws kc=0
        f16x8 ws1 = wv[(4 + ct) * 64 + l];        // Ws kc=1
        f16x8 wn0 = wv[(8 + ct) * 64 + l];        // Wn kc=0
        f16x8 wn1 = wv[(12 + ct) * 64 + l];       // Wn kc=1
        float bj = bsage[ct * 16 + lr];
        f32x4 acc = {bj, bj, bj, bj};
        acc = __builtin_amdgcn_mfma_f32_16x16x32_f16(xa0, ws0, acc, 0, 0, 0);
        acc = __builtin_amdgcn_mfma_f32_16x16x32_f16(xa1, ws1, acc, 0, 0, 0);
        acc = __builtin_amdgcn_mfma_f32_16x16x32_f16(ma0, wn0, acc, 0, 0, 0);
        acc = __builtin_amdgcn_mfma_f32_16x16x32_f16(ma1, wn1, acc, 0, 0, 0);
        #pragma unroll
        for (int i = 0; i < 4; ++i) {
            int rr = w * 16 + lg * 4 + i;
            int cc = ct * 16 + lr;
            H16[rr * 64 + ((((cc >> 3) ^ (rr & 7)) << 3) | (cc & 7))] =
                (f16)fmaxf(acc[i], 0.0f);
        }
    }
    __syncthreads();

    // ---- phase 2: A = H Q1, B = H Q2 ----
    f16x8 ha0 = *(const f16x8*)
        &H16[arow * 64 + (((kb >> 3) ^ (arow & 7)) << 3)];
    f16x8 ha1 = *(const f16x8*)
        &H16[arow * 64 + ((((kb + 32) >> 3) ^ (arow & 7)) << 3)];
    #pragma unroll
    for (int ct = 0; ct < 4; ++ct) {
        f16x8 q10 = wv[(16 + ct) * 64 + l];       // Q1 kc=0
        f16x8 q11 = wv[(20 + ct) * 64 + l];       // Q1 kc=1
        f16x8 q20 = wv[(24 + ct) * 64 + l];       // Q2 kc=0
        f16x8 q21 = wv[(28 + ct) * 64 + l];       // Q2 kc=1
        f32x4 aA = {0.f, 0.f, 0.f, 0.f};
        f32x4 aB = {0.f, 0.f, 0.f, 0.f};
        aA = __builtin_amdgcn_mfma_f32_16x16x32_f16(ha0, q10, aA, 0, 0, 0);
        aA = __builtin_amdgcn_mfma_f32_16x16x32_f16(ha1, q11, aA, 0, 0, 0);
        aB = __builtin_amdgcn_mfma_f32_16x16x32_f16(ha0, q20, aB, 0, 0, 0);
        aB = __builtin_amdgcn_mfma_f32_16x16x32_f16(ha1, q21, aB, 0, 0, 0);
        #pragma unroll
        for (int i = 0; i < 4; ++i) {
            int gr = nbase + w * 16 + lg * 4 + i;
            if (gr < NN) {
                int cc = ct * 16 + lr;
                A[(size_t)gr * 64 + cc] = aA[i];
                B16[(size_t)gr * 64 + cc] = (f16)aB[i];
            }
        }
    }
}

// ---------- pass 5: wave-per-node out-edge reduction (f16 B), 8-deep ILP ----
__global__ __launch_bounds__(256) void edge_out(
    const float* __restrict__ A, const f16* __restrict__ B16,
    const float* __restrict__ Qb, const int* __restrict__ off_src,
    const int* __restrict__ csr, float* __restrict__ out) {
    int wid = (int)(((long long)blockIdx.x * blockDim.x + threadIdx.x) >> 6);
    int j = threadIdx.x & 63;
    if (wid >= NN) return;
    float aq = A[(size_t)wid * NH + j] + Qb[j];
    int e0 = off_src[wid], e1 = off_src[wid + 1];
    const f16* Bj = B16 + j;
    float s0 = 0, s1 = 0, s2 = 0, s3 = 0, s4 = 0, s5 = 0, s6 = 0, s7 = 0;
    int e = e0;
    for (; e + 8 <= e1; e += 8) {
        int i0 = cidx(csr[e + 0]), i1 = cidx(csr[e + 1]);
        int i2 = cidx(csr[e + 2]), i3 = cidx(csr[e + 3]);
        int i4 = cidx(csr[e + 4]), i5 = cidx(csr[e + 5]);
        int i6 = cidx(csr[e + 6]), i7 = cidx(csr[e + 7]);
        float t0 = aq + (float)Bj[(size_t)i0 * NH]; s0 += t0 * t0;
        float t1 = aq + (float)Bj[(size_t)i1 * NH]; s1 += t1 * t1;
        float t2 = aq + (float)Bj[(size_t)i2 * NH]; s2 += t2 * t2;
        float t3 = aq + (float)Bj[(size_t)i3 * NH]; s3 += t3 * t3;
        float t4 = aq + (float)Bj[(size_t)i4 * NH]; s4 += t4 * t4;
        float t5 = aq + (float)Bj[(size_t)i5 * NH]; s5 += t5 * t5;
        float t6 = aq + (float)Bj[(size_t)i6 * NH]; s6 += t6 * t6;
        float t7 = aq + (float)Bj[(size_t)i7 * NH]; s7 += t7 * t7;
    }
    for (; e < e1; ++e) {
        float t = aq + (float)Bj[(size_t)cidx(csr[e]) * NH];
        s0 += t * t;
    }
    float acc = ((s0 + s1) + (s2 + s3)) + ((s4 + s5) + (s6 + s7));
    out[(size_t)wid * NH + j] = tanhf(acc / fmaxf((float)(e1 - e0), 1.0f));
}

extern "C" void kernel_launch(void* const* d_in, const int* in_sizes, int n_in,
                              void* d_out, int out_size, void* d_ws, size_t ws_size,
                              hipStream_t stream) {
    const float* X      = (const float*)d_in[0];
    const int*   ei     = (const int*)d_in[1];   // [2, NE] int32
    const float* Wself  = (const float*)d_in[2];
    const float* Wneigh = (const float*)d_in[3];
    const float* bsage  = (const float*)d_in[4];
    const float* Qw     = (const float*)d_in[5];
    const float* Qb     = (const float*)d_in[6];
    const int* src = ei;
    const int* dst = ei + NE;

    float* out = (float*)d_out;

    // workspace layout (~44 MB). M16 aliases pairs: pairs is dead after
    // sort_pass, gather_mean runs after sort_pass -> safe.
    float* A   = (float*)d_ws;                       // NN*NH f32 (output A)
    f16* X16   = (f16*)(A + (size_t)NN * NH);        // NN*NH f16
    f16* B16   = X16 + (size_t)NN * NH;              // NN*NH f16
    unsigned* pairs = (unsigned*)(B16 + (size_t)NN * NH); // NBKT*CAP u32
    f16* M16   = (f16*)pairs;                        // aliases pairs
    int* csr   = (int*)(pairs + (size_t)NBKT * CAP); // 2*NE
    int* off   = csr + 2 * NE;                       // NKEY+1
    int* gcnt  = off + NKEY + 1;                     // NBKT
    f16* wp    = (f16*)(gcnt + NBKT);                // 16384 f16 (32 KB)

    hipMemsetAsync(gcnt, 0, NBKT * sizeof(int), stream);

    convert_x<<<(NN * NH / 4 + 255) / 256, 256, 0, stream>>>(X, X16);
    pack_w<<<64, 256, 0, stream>>>(Wself, Wneigh, Qw, wp);
    bin_pass<<<512, 256, 0, stream>>>(src, dst, gcnt, pairs);
    sort_pass<<<NBKT, 1024, 0, stream>>>(pairs, gcnt, off, csr);
    gather_mean<<<(NN + 3) / 4, 256, 0, stream>>>(X16, off + NN, csr, M16);
    node_gemm<<<(NN + 63) / 64, 256, 0, stream>>>(X16, M16, wp, bsage, A, B16);
    edge_out<<<(NN + 3) / 4, 256, 0, stream>>>(A, B16, Qb, off, csr, out);
}

// Round 15
// 124.065 us; speedup vs baseline: 1.4962x; 1.1654x over previous
//
#include <hip/hip_runtime.h>
#include <math.h>

#define NN 50000
#define NE 1000000
#define NH 64
#define NKEY 100000      // 2*NN combined key space (src | NN+dst)
#define SPAN 512         // keys per bucket
#define NBKT 196         // ceil(NKEY / SPAN)
#define CAP 12288        // bucket capacity (mean 10240, generous)
#define CH 32            // LDS staging entries per bucket (pow2 for shift math)

typedef _Float16 f16;
typedef _Float16 f16x4 __attribute__((ext_vector_type(4)));
typedef _Float16 f16x8 __attribute__((ext_vector_type(8)));
typedef float f32x4 __attribute__((ext_vector_type(4)));

// ---------- pass 0: X -> f16 table AND weights -> fragment-packed f16 -------
__global__ __launch_bounds__(256) void pack_all(
    const float* __restrict__ X, f16* __restrict__ X16,
    const float* __restrict__ Ws, const float* __restrict__ Wn,
    const float* __restrict__ Qw, f16* __restrict__ wp) {
    int i = blockIdx.x * 256 + threadIdx.x;
    if (i < NN * NH / 4) {
        float4 v = ((const float4*)X)[i];
        f16x4 o = {(f16)v.x, (f16)v.y, (f16)v.z, (f16)v.w};
        ((f16x4*)X16)[i] = o;
    }
    if (i < 16384) {
        int m  = i >> 12;
        int kc = (i >> 11) & 1;
        int l  = (i >> 3) & 63;
        int e  = i & 7;
        int ct = (i >> 9) & 3;
        int k  = kc * 32 + (l >> 4) * 8 + e;
        int j  = ct * 16 + (l & 15);
        const float* W = (m == 0) ? Ws : (m == 1) ? Wn : (m == 2) ? Qw
                                                      : (Qw + 4096);
        wp[i] = (f16)W[k * 64 + j];
    }
}

// ---------- binning helpers -------------------------------------------------
__device__ __forceinline__ void push_pair(int key, int val, int* cnt,
                                          unsigned* buf, int* gcnt,
                                          unsigned* __restrict__ pairs) {
    int b = key >> 9;
    unsigned pk = ((unsigned)val << 9) | (unsigned)(key & 511);
    int slot = atomicAdd(&cnt[b], 1);           // LDS atomic
    if (slot < CH) {
        buf[b * CH + slot] = pk;
    } else {                                     // rare overflow: direct path
        int g = atomicAdd(&gcnt[b], 1);
        if (g < CAP) pairs[(size_t)b * CAP + g] = pk;
    }
}

__device__ __forceinline__ void flush_coop(int* cnt, int* s_fc, int* s_g,
                                           unsigned* buf, int* gcnt,
                                           unsigned* __restrict__ pairs) {
    __syncthreads();
    int t = threadIdx.x;
    if (t < NBKT) {
        int fc = cnt[t]; if (fc > CH) fc = CH;
        s_fc[t] = fc;
        s_g[t] = (fc > 0) ? atomicAdd(&gcnt[t], fc) : 0;
    }
    __syncthreads();
    for (int i = t; i < NBKT * CH; i += 256) {
        int b = i >> 5, s = i & 31;              // CH == 32
        if (s < s_fc[b])
            pairs[(size_t)b * CAP + s_g[b] + s] = buf[i];
    }
    __syncthreads();
    if (t < NBKT) cnt[t] = 0;
    __syncthreads();
}

// ---------- pass 1: LDS-staged binning of 2M (key,val) pairs ----------------
__global__ __launch_bounds__(256) void bin_pass(
    const int* __restrict__ src, const int* __restrict__ dst,
    int* __restrict__ gcnt, unsigned* __restrict__ pairs) {
    __shared__ int cnt[NBKT];
    __shared__ int s_fc[NBKT];
    __shared__ int s_g[NBKT];
    __shared__ unsigned buf[NBKT * CH];
    for (int b = threadIdx.x; b < NBKT; b += 256) cnt[b] = 0;
    __syncthreads();
    int r = 0;
    for (int base = blockIdx.x * 256; base < NE; base += gridDim.x * 256) {
        int e = base + threadIdx.x;
        if (e < NE) {
            int s = src[e], d = dst[e];
            push_pair(s, d, cnt, buf, gcnt, pairs);       // out-edge of s
            push_pair(NN + d, s, cnt, buf, gcnt, pairs);  // in-edge of d
        }
        if ((++r & 7) == 0) flush_coop(cnt, s_fc, s_g, buf, gcnt, pairs);
    }
    flush_coop(cnt, s_fc, s_g, buf, gcnt, pairs);
}

// ---------- pass 2: per-bucket counting sort + off/csr (scan folded in) -----
__global__ __launch_bounds__(1024) void sort_pass(
    const unsigned* __restrict__ pairs, const int* __restrict__ gcnt,
    int* __restrict__ off, int* __restrict__ csr) {
    __shared__ int hist[SPAN];
    __shared__ int scn[SPAN];
    __shared__ int bsc[256];
    int k = blockIdx.x;
    int t = threadIdx.x;

    if (t < 256) bsc[t] = (t < NBKT) ? gcnt[t] : 0;
    __syncthreads();
    for (int o = 1; o < 256; o <<= 1) {
        int u = 0;
        if (t < 256 && t >= o) u = bsc[t - o];
        __syncthreads();
        if (t < 256) bsc[t] += u;
        __syncthreads();
    }
    int base = (k > 0) ? bsc[k - 1] : 0;
    int n = gcnt[k]; if (n > CAP) n = CAP;
    const unsigned* bp = pairs + (size_t)k * CAP;
    if (k == 0 && t == 0) off[NKEY] = 2 * NE;    // sentinel

    if (t < SPAN) hist[t] = 0;
    __syncthreads();
    for (int i = t; i < n; i += 1024)
        atomicAdd(&hist[bp[i] & 511], 1);
    __syncthreads();
    if (t < SPAN) scn[t] = hist[t];
    __syncthreads();
    for (int o = 1; o < SPAN; o <<= 1) {
        int u = 0;
        if (t < SPAN && t >= o) u = scn[t - o];
        __syncthreads();
        if (t < SPAN) scn[t] += u;
        __syncthreads();
    }
    if (t < SPAN) {
        int ex = base + scn[t] - hist[t];   // absolute exclusive prefix
        int gk = k * SPAN + t;
        if (gk < NKEY) off[gk] = ex;
        scn[t] = ex;                        // reuse as cursor
    }
    __syncthreads();
    for (int i = t; i < n; i += 1024) {
        unsigned p = bp[i];
        int pos = atomicAdd(&scn[p & 511], 1);   // LDS atomic
        csr[pos] = (int)(p >> 9);                // block-local global store
    }
}

// clamp gathered index (protects rocprof dispatch-replay from stale buffers)
__device__ __forceinline__ int cidx(int i) {
    return max(0, min(i, NN - 1));
}

__device__ __forceinline__ float4 f16x4_to_f32(f16x4 r) {
    float4 o; o.x = (float)r.x; o.y = (float)r.y;
    o.z = (float)r.z; o.w = (float)r.w; return o;
}
__device__ __forceinline__ float4 shfl_xor4(float4 v, int m) {
    float4 o;
    o.x = __shfl_xor(v.x, m, 64); o.y = __shfl_xor(v.y, m, 64);
    o.z = __shfl_xor(v.z, m, 64); o.w = __shfl_xor(v.w, m, 64);
    return o;
}

// ---------- pass 3: gather-mean, 16-lane-group rows (4 edges / load instr) --
// wave = node; lane l: cols 4q..4q+3 (q=l&15) of edge-stream g=l>>4.
__global__ __launch_bounds__(256) void gather_mean(
    const f16* __restrict__ X16, const int* __restrict__ off_dst,
    const int* __restrict__ csr, f16* __restrict__ M16) {
    int wid = (int)(((long long)blockIdx.x * blockDim.x + threadIdx.x) >> 6);
    int l = threadIdx.x & 63;
    int q = l & 15, g = l >> 4;
    if (wid >= NN) return;
    int e0 = off_dst[wid], e1 = off_dst[wid + 1];
    int deg = e1 - e0;
    const f16x4* Xq = (const f16x4*)(X16 + 4 * q);   // row base + col offset
    float4 s0 = {0,0,0,0}, s1 = {0,0,0,0}, s2 = {0,0,0,0}, s3 = {0,0,0,0};
    int Tf = deg >> 2;          // fully-valid slots (all 4 streams)
    int t = 0;
    for (; t + 4 <= Tf; t += 4) {
        int i0 = cidx(csr[e0 + 4 * (t + 0) + g]);
        int i1 = cidx(csr[e0 + 4 * (t + 1) + g]);
        int i2 = cidx(csr[e0 + 4 * (t + 2) + g]);
        int i3 = cidx(csr[e0 + 4 * (t + 3) + g]);
        float4 r0 = f16x4_to_f32(Xq[(size_t)i0 * 16]);
        float4 r1 = f16x4_to_f32(Xq[(size_t)i1 * 16]);
        float4 r2 = f16x4_to_f32(Xq[(size_t)i2 * 16]);
        float4 r3 = f16x4_to_f32(Xq[(size_t)i3 * 16]);
        s0.x += r0.x; s0.y += r0.y; s0.z += r0.z; s0.w += r0.w;
        s1.x += r1.x; s1.y += r1.y; s1.z += r1.z; s1.w += r1.w;
        s2.x += r2.x; s2.y += r2.y; s2.z += r2.z; s2.w += r2.w;
        s3.x += r3.x; s3.y += r3.y; s3.z += r3.z; s3.w += r3.w;
    }
    for (; t < Tf; ++t) {
        int i0 = cidx(csr[e0 + 4 * t + g]);
        float4 r0 = f16x4_to_f32(Xq[(size_t)i0 * 16]);
        s0.x += r0.x; s0.y += r0.y; s0.z += r0.z; s0.w += r0.w;
    }
    int rem = deg & 3;
    if (rem) {                  // one masked slot, streams g<rem valid
        int e = e0 + 4 * Tf + g;
        float m = (g < rem) ? 1.0f : 0.0f;
        int i0 = cidx(csr[(g < rem) ? e : (e1 - 1)]);
        float4 r0 = f16x4_to_f32(Xq[(size_t)i0 * 16]);
        s0.x += m * r0.x; s0.y += m * r0.y;
        s0.z += m * r0.z; s0.w += m * r0.w;
    }
    float4 s;
    s.x = (s0.x + s1.x) + (s2.x + s3.x);
    s.y = (s0.y + s1.y) + (s2.y + s3.y);
    s.z = (s0.z + s1.z) + (s2.z + s3.z);
    s.w = (s0.w + s1.w) + (s2.w + s3.w);
    float4 u = shfl_xor4(s, 16);
    s.x += u.x; s.y += u.y; s.z += u.z; s.w += u.w;
    u = shfl_xor4(s, 32);
    s.x += u.x; s.y += u.y; s.z += u.z; s.w += u.w;
    if (l < 16) {
        float inv = 1.0f / fmaxf((float)deg, 1.0f);
        f16x4 o = {(f16)(s.x * inv), (f16)(s.y * inv),
                   (f16)(s.z * inv), (f16)(s.w * inv)};
        *(f16x4*)&M16[(size_t)wid * NH + 4 * q] = o;
    }
}

// ---------- pass 4: node GEMM v8 — MFMA f16 (unchanged, proven) -------------
__global__ __launch_bounds__(256) void node_gemm(
    const f16* __restrict__ X16, const f16* __restrict__ M16,
    const f16* __restrict__ wp, const float* __restrict__ bsage,
    float* __restrict__ A, f16* __restrict__ B16) {
    __shared__ f16 H16[64 * 64];
    const int T = threadIdx.x;
    const int l = T & 63, w = T >> 6;
    const int lr = l & 15, lg = l >> 4;
    const int nbase = blockIdx.x * 64;
    const int arow = w * 16 + lr;
    const int node = min(nbase + arow, NN - 1);
    const int kb = lg * 8;

    const f16x8* wv = (const f16x8*)wp;
    f16x8 xa0 = *(const f16x8*)&X16[(size_t)node * 64 + kb];
    f16x8 xa1 = *(const f16x8*)&X16[(size_t)node * 64 + 32 + kb];
    f16x8 ma0 = *(const f16x8*)&M16[(size_t)node * 64 + kb];
    f16x8 ma1 = *(const f16x8*)&M16[(size_t)node * 64 + 32 + kb];

    #pragma unroll
    for (int ct = 0; ct < 4; ++ct) {
        f16x8 ws0 = wv[(0 + ct) * 64 + l];
        f16x8 ws1 = wv[(4 + ct) * 64 + l];
        f16x8 wn0 = wv[(8 + ct) * 64 + l];
        f16x8 wn1 = wv[(12 + ct) * 64 + l];
        float bj = bsage[ct * 16 + lr];
        f32x4 acc = {bj, bj, bj, bj};
        acc = __builtin_amdgcn_mfma_f32_16x16x32_f16(xa0, ws0, acc, 0, 0, 0);
        acc = __builtin_amdgcn_mfma_f32_16x16x32_f16(xa1, ws1, acc, 0, 0, 0);
        acc = __builtin_amdgcn_mfma_f32_16x16x32_f16(ma0, wn0, acc, 0, 0, 0);
        acc = __builtin_amdgcn_mfma_f32_16x16x32_f16(ma1, wn1, acc, 0, 0, 0);
        #pragma unroll
        for (int i = 0; i < 4; ++i) {
            int rr = w * 16 + lg * 4 + i;
            int cc = ct * 16 + lr;
            H16[rr * 64 + ((((cc >> 3) ^ (rr & 7)) << 3) | (cc & 7))] =
                (f16)fmaxf(acc[i], 0.0f);
        }
    }
    __syncthreads();

    f16x8 ha0 = *(const f16x8*)
        &H16[arow * 64 + (((kb >> 3) ^ (arow & 7)) << 3)];
    f16x8 ha1 = *(const f16x8*)
        &H16[arow * 64 + ((((kb + 32) >> 3) ^ (arow & 7)) << 3)];
    #pragma unroll
    for (int ct = 0; ct < 4; ++ct) {
        f16x8 q10 = wv[(16 + ct) * 64 + l];
        f16x8 q11 = wv[(20 + ct) * 64 + l];
        f16x8 q20 = wv[(24 + ct) * 64 + l];
        f16x8 q21 = wv[(28 + ct) * 64 + l];
        f32x4 aA = {0.f, 0.f, 0.f, 0.f};
        f32x4 aB = {0.f, 0.f, 0.f, 0.f};
        aA = __builtin_amdgcn_mfma_f32_16x16x32_f16(ha0, q10, aA, 0, 0, 0);
        aA = __builtin_amdgcn_mfma_f32_16x16x32_f16(ha1, q11, aA, 0, 0, 0);
        aB = __builtin_amdgcn_mfma_f32_16x16x32_f16(ha0, q20, aB, 0, 0, 0);
        aB = __builtin_amdgcn_mfma_f32_16x16x32_f16(ha1, q21, aB, 0, 0, 0);
        #pragma unroll
        for (int i = 0; i < 4; ++i) {
            int gr = nbase + w * 16 + lg * 4 + i;
            if (gr < NN) {
                int cc = ct * 16 + lr;
                A[(size_t)gr * 64 + cc] = aA[i];
                B16[(size_t)gr * 64 + cc] = (f16)aB[i];
            }
        }
    }
}

// ---------- pass 5: edge_out, 16-lane-group rows (4 edges / load instr) -----
__global__ __launch_bounds__(256) void edge_out(
    const float* __restrict__ A, const f16* __restrict__ B16,
    const float* __restrict__ Qb, const int* __restrict__ off_src,
    const int* __restrict__ csr, float* __restrict__ out) {
    int wid = (int)(((long long)blockIdx.x * blockDim.x + threadIdx.x) >> 6);
    int l = threadIdx.x & 63;
    int q = l & 15, g = l >> 4;
    if (wid >= NN) return;
    float4 aq = *(const float4*)&A[(size_t)wid * NH + 4 * q];
    float4 qb = *(const float4*)&Qb[4 * q];
    aq.x += qb.x; aq.y += qb.y; aq.z += qb.z; aq.w += qb.w;
    int e0 = off_src[wid], e1 = off_src[wid + 1];
    int deg = e1 - e0;
    const f16x4* Bq = (const f16x4*)(B16 + 4 * q);
    float4 s0 = {0,0,0,0}, s1 = {0,0,0,0}, s2 = {0,0,0,0}, s3 = {0,0,0,0};
    int Tf = deg >> 2;
    int t = 0;
#define EACC(sv, rv)                                                   \
    { float4 tv;                                                       \
      tv.x = aq.x + rv.x; tv.y = aq.y + rv.y;                          \
      tv.z = aq.z + rv.z; tv.w = aq.w + rv.w;                          \
      sv.x += tv.x * tv.x; sv.y += tv.y * tv.y;                        \
      sv.z += tv.z * tv.z; sv.w += tv.w * tv.w; }
    for (; t + 4 <= Tf; t += 4) {
        int i0 = cidx(csr[e0 + 4 * (t + 0) + g]);
        int i1 = cidx(csr[e0 + 4 * (t + 1) + g]);
        int i2 = cidx(csr[e0 + 4 * (t + 2) + g]);
        int i3 = cidx(csr[e0 + 4 * (t + 3) + g]);
        float4 r0 = f16x4_to_f32(Bq[(size_t)i0 * 16]);
        float4 r1 = f16x4_to_f32(Bq[(size_t)i1 * 16]);
        float4 r2 = f16x4_to_f32(Bq[(size_t)i2 * 16]);
        float4 r3 = f16x4_to_f32(Bq[(size_t)i3 * 16]);
        EACC(s0, r0) EACC(s1, r1) EACC(s2, r2) EACC(s3, r3)
    }
    for (; t < Tf; ++t) {
        int i0 = cidx(csr[e0 + 4 * t + g]);
        float4 r0 = f16x4_to_f32(Bq[(size_t)i0 * 16]);
        EACC(s0, r0)
    }
    int rem = deg & 3;
    if (rem) {
        int e = e0 + 4 * Tf + g;
        float m = (g < rem) ? 1.0f : 0.0f;
        int i0 = cidx(csr[(g < rem) ? e : (e1 - 1)]);
        float4 r0 = f16x4_to_f32(Bq[(size_t)i0 * 16]);
        float4 tv;
        tv.x = aq.x + r0.x; tv.y = aq.y + r0.y;
        tv.z = aq.z + r0.z; tv.w = aq.w + r0.w;
        s0.x += m * tv.x * tv.x; s0.y += m * tv.y * tv.y;
        s0.z += m * tv.z * tv.z; s0.w += m * tv.w * tv.w;
    }
#undef EACC
    float4 s;
    s.x = (s0.x + s1.x) + (s2.x + s3.x);
    s.y = (s0.y + s1.y) + (s2.y + s3.y);
    s.z = (s0.z + s1.z) + (s2.z + s3.z);
    s.w = (s0.w + s1.w) + (s2.w + s3.w);
    float4 u = shfl_xor4(s, 16);
    s.x += u.x; s.y += u.y; s.z += u.z; s.w += u.w;
    u = shfl_xor4(s, 32);
    s.x += u.x; s.y += u.y; s.z += u.z; s.w += u.w;
    if (l < 16) {
        float inv = 1.0f / fmaxf((float)deg, 1.0f);
        float4 o;
        o.x = tanhf(s.x * inv); o.y = tanhf(s.y * inv);
        o.z = tanhf(s.z * inv); o.w = tanhf(s.w * inv);
        *(float4*)&out[(size_t)wid * NH + 4 * q] = o;
    }
}

extern "C" void kernel_launch(void* const* d_in, const int* in_sizes, int n_in,
                              void* d_out, int out_size, void* d_ws, size_t ws_size,
                              hipStream_t stream) {
    const float* X      = (const float*)d_in[0];
    const int*   ei     = (const int*)d_in[1];   // [2, NE] int32
    const float* Wself  = (const float*)d_in[2];
    const float* Wneigh = (const float*)d_in[3];
    const float* bsage  = (const float*)d_in[4];
    const float* Qw     = (const float*)d_in[5];
    const float* Qb     = (const float*)d_in[6];
    const int* src = ei;
    const int* dst = ei + NE;

    float* out = (float*)d_out;

    // workspace layout (~44 MB). M16 aliases pairs (pairs dead after sort).
    float* A   = (float*)d_ws;                       // NN*NH f32 (output A)
    f16* X16   = (f16*)(A + (size_t)NN * NH);        // NN*NH f16
    f16* B16   = X16 + (size_t)NN * NH;              // NN*NH f16
    unsigned* pairs = (unsigned*)(B16 + (size_t)NN * NH); // NBKT*CAP u32
    f16* M16   = (f16*)pairs;                        // aliases pairs
    int* csr   = (int*)(pairs + (size_t)NBKT * CAP); // 2*NE
    int* off   = csr + 2 * NE;                       // NKEY+1
    int* gcnt  = off + NKEY + 1;                     // NBKT
    f16* wp    = (f16*)(gcnt + NBKT);                // 16384 f16 (32 KB)

    hipMemsetAsync(gcnt, 0, NBKT * sizeof(int), stream);

    pack_all<<<(NN * NH / 4 + 255) / 256, 256, 0, stream>>>(X, X16, Wself,
                                                            Wneigh, Qw, wp);
    bin_pass<<<512, 256, 0, stream>>>(src, dst, gcnt, pairs);
    sort_pass<<<NBKT, 1024, 0, stream>>>(pairs, gcnt, off, csr);
    gather_mean<<<(NN + 3) / 4, 256, 0, stream>>>(X16, off + NN, csr, M16);
    node_gemm<<<(NN + 63) / 64, 256, 0, stream>>>(X16, M16, wp, bsage, A, B16);
    edge_out<<<(NN + 3) / 4, 256, 0, stream>>>(A, B16, Qb, off, csr, out);
}